// Round 2
// baseline (2615.631 us; speedup 1.0000x reference)
//
#include <hip/hip_runtime.h>

#define N_USERS 100000
#define N_ITEMS 50000
#define N_NODES 150000
#define NNZ 1500000
#define BATCH 1048576
#define DIM 64

// Zero the two H accumulators (graph-capture-safe replacement for hipMemsetAsync).
__global__ void zero_ws(float4* __restrict__ p, int n4) {
    int i = blockIdx.x * blockDim.x + threadIdx.x;
    if (i < n4) p[i] = make_float4(0.f, 0.f, 0.f, 0.f);
}

// One 16-lane group per edge; lane s handles dims [4s, 4s+4).
__global__ void spmm_scatter(const int* __restrict__ rows,
                             const int* __restrict__ cols,
                             const float* __restrict__ vals,
                             const float* __restrict__ Hu,
                             const float* __restrict__ Hi,
                             float* __restrict__ out) {
    int gid = blockIdx.x * blockDim.x + threadIdx.x;
    int e = gid >> 4;
    int s = gid & 15;
    if (e >= NNZ) return;
    int r = rows[e];
    int c = cols[e];
    float v = vals[e];
    const float* src = (c < N_USERS) ? (Hu + (size_t)c * DIM)
                                     : (Hi + (size_t)(c - N_USERS) * DIM);
    float4 x = *reinterpret_cast<const float4*>(src + s * 4);
    float* dst = out + (size_t)r * DIM + s * 4;
    atomicAdd(dst + 0, v * x.x);
    atomicAdd(dst + 1, v * x.y);
    atomicAdd(dst + 2, v * x.z);
    atomicAdd(dst + 3, v * x.w);
}

// One 16-lane group per batch element; float4 dot over 64 dims + shfl reduce.
__global__ void pred_kernel(const int* __restrict__ u_idx,
                            const int* __restrict__ i_idx,
                            const float* __restrict__ U,
                            const float* __restrict__ I,
                            const float* __restrict__ bu,
                            const float* __restrict__ bi,
                            const float* __restrict__ mu,
                            float* __restrict__ out) {
    int gid = blockIdx.x * blockDim.x + threadIdx.x;
    int b = gid >> 4;
    int s = gid & 15;
    if (b >= BATCH) return;
    int u = u_idx[b];
    int it = i_idx[b];
    float4 a = *reinterpret_cast<const float4*>(U + (size_t)u * DIM + s * 4);
    float4 c = *reinterpret_cast<const float4*>(I + (size_t)it * DIM + s * 4);
    float p = a.x * c.x + a.y * c.y + a.z * c.z + a.w * c.w;
    p += __shfl_xor(p, 1);
    p += __shfl_xor(p, 2);
    p += __shfl_xor(p, 4);
    p += __shfl_xor(p, 8);
    if (s == 0) out[b] = p + bu[u] + bi[it] + mu[0];
}

extern "C" void kernel_launch(void* const* d_in, const int* in_sizes, int n_in,
                              void* d_out, int out_size, void* d_ws, size_t ws_size,
                              hipStream_t stream) {
    const int*   u_idx  = (const int*)d_in[0];
    const int*   i_idx  = (const int*)d_in[1];
    const int*   A_rows = (const int*)d_in[2];
    const int*   A_cols = (const int*)d_in[3];
    const float* A_vals = (const float*)d_in[4];
    const float* Eu     = (const float*)d_in[5];
    const float* Ei     = (const float*)d_in[6];
    const float* bu     = (const float*)d_in[7];
    const float* bi     = (const float*)d_in[8];
    const float* mu     = (const float*)d_in[9];
    float* out = (float*)d_out;

    float* H1 = (float*)d_ws;
    float* H2 = H1 + (size_t)N_NODES * DIM;

    // Zero both accumulation buffers every call via a kernel (graph-safe).
    const int n4 = 2 * N_NODES * DIM / 4;
    zero_ws<<<(n4 + 255) / 256, 256, 0, stream>>>((float4*)d_ws, n4);

    const int spmm_threads = NNZ * 16;
    const int spmm_blocks  = (spmm_threads + 255) / 256;

    // Layer 1: H1 = A @ [Eu; Ei]
    spmm_scatter<<<spmm_blocks, 256, 0, stream>>>(A_rows, A_cols, A_vals, Eu, Ei, H1);
    // Layer 2: H2 = A @ H1
    spmm_scatter<<<spmm_blocks, 256, 0, stream>>>(A_rows, A_cols, A_vals,
                                                  H1, H1 + (size_t)N_USERS * DIM, H2);

    // pred = sum(U[u]*I[i]) + bu[u] + bi[i] + mu
    const int pred_threads = BATCH * 16;
    const int pred_blocks  = (pred_threads + 255) / 256;
    pred_kernel<<<pred_blocks, 256, 0, stream>>>(u_idx, i_idx,
                                                 H2, H2 + (size_t)N_USERS * DIM,
                                                 bu, bi, mu, out);
}

// Round 3
// 482.428 us; speedup vs baseline: 5.4218x; 5.4218x over previous
//
#include <hip/hip_runtime.h>

#define N_USERS 100000
#define N_ITEMS 50000
#define N_NODES 150000
#define NNZ 1500000
#define BATCH 1048576
#define DIM 64

#define SCAN_CHUNK 1024
#define N_CHUNKS ((N_NODES + SCAN_CHUNK - 1) / SCAN_CHUNK)   // 147

// ---------- generic zero (graph-capture-safe) ----------
__global__ void zero_ws(float4* __restrict__ p, int n4) {
    int i = blockIdx.x * blockDim.x + threadIdx.x;
    if (i < n4) p[i] = make_float4(0.f, 0.f, 0.f, 0.f);
}

// ---------- CSR build ----------
__global__ void count_rows(const int* __restrict__ rows, int* __restrict__ counts) {
    int e = blockIdx.x * blockDim.x + threadIdx.x;
    if (e < NNZ) atomicAdd(&counts[rows[e]], 1);
}

// Per-chunk exclusive scan of counts -> row_ptr (chunk-local); chunk totals -> partials.
__global__ void scan_chunks(const int* __restrict__ counts,
                            int* __restrict__ row_ptr,
                            int* __restrict__ partials) {
    __shared__ int sdata[SCAN_CHUNK];
    int tid = threadIdx.x;
    int i = blockIdx.x * SCAN_CHUNK + tid;
    int x = (i < N_NODES) ? counts[i] : 0;
    sdata[tid] = x;
    __syncthreads();
    for (int off = 1; off < SCAN_CHUNK; off <<= 1) {
        int t = (tid >= off) ? sdata[tid - off] : 0;
        __syncthreads();
        sdata[tid] += t;
        __syncthreads();
    }
    int incl = sdata[tid];
    if (i < N_NODES) row_ptr[i] = incl - x;   // exclusive within chunk
    if (tid == SCAN_CHUNK - 1) partials[blockIdx.x] = incl;
}

// Single-block exclusive scan of the (147) chunk totals.
__global__ void scan_partials(int* __restrict__ partials, int nb) {
    __shared__ int sdata[256];
    int tid = threadIdx.x;
    if (tid < nb) sdata[tid] = partials[tid];
    __syncthreads();
    if (tid == 0) {
        int run = 0;
        for (int b = 0; b < nb; ++b) { int t = sdata[b]; sdata[b] = run; run += t; }
    }
    __syncthreads();
    if (tid < nb) partials[tid] = sdata[tid];
}

// Add chunk offsets; produce final row_ptr, copy to cursor; set row_ptr[N]=NNZ.
__global__ void finalize_ptr(int* __restrict__ row_ptr,
                             const int* __restrict__ partials,
                             int* __restrict__ cursor) {
    int i = blockIdx.x * blockDim.x + threadIdx.x;
    if (i < N_NODES) {
        int p = row_ptr[i] + partials[i >> 10];
        row_ptr[i] = p;
        cursor[i] = p;
    }
    if (i == 0) row_ptr[N_NODES] = NNZ;
}

// Bucket edges into CSR order (order within a row is arbitrary — sum is order-insensitive within tolerance).
__global__ void scatter_edges(const int* __restrict__ rows,
                              const int* __restrict__ cols,
                              const float* __restrict__ vals,
                              int* __restrict__ cursor,
                              int* __restrict__ colS,
                              float* __restrict__ valS) {
    int e = blockIdx.x * blockDim.x + threadIdx.x;
    if (e >= NNZ) return;
    int r = rows[e];
    int pos = atomicAdd(&cursor[r], 1);
    colS[pos] = cols[e];
    valS[pos] = vals[e];
}

// ---------- SpMM gather: one wave64 per row, lane = dim ----------
__global__ void spmm_gather(const int* __restrict__ row_ptr,
                            const int* __restrict__ colS,
                            const float* __restrict__ valS,
                            const float* __restrict__ Hu,
                            const float* __restrict__ Hi,
                            float* __restrict__ out) {
    int wid  = (blockIdx.x * blockDim.x + threadIdx.x) >> 6;
    int lane = threadIdx.x & 63;
    if (wid >= N_NODES) return;
    int beg = row_ptr[wid];
    int end = row_ptr[wid + 1];
    int n = end - beg;
    // Preload up to 64 edges into lanes; broadcast with shfl (kills per-edge scalar-load latency).
    int   c_l = (lane < n) ? colS[beg + lane] : 0;
    float v_l = (lane < n) ? valS[beg + lane] : 0.f;
    float acc = 0.f;
    int nn = (n < 64) ? n : 64;
    for (int k = 0; k < nn; ++k) {
        int   c = __shfl(c_l, k);
        float v = __shfl(v_l, k);
        const float* src = (c < N_USERS) ? (Hu + (size_t)c * DIM)
                                         : (Hi + (size_t)(c - N_USERS) * DIM);
        acc += v * src[lane];
    }
    for (int k = 64; k < n; ++k) {           // Poisson(10) rows: essentially never taken
        int   c = colS[beg + k];
        float v = valS[beg + k];
        const float* src = (c < N_USERS) ? (Hu + (size_t)c * DIM)
                                         : (Hi + (size_t)(c - N_USERS) * DIM);
        acc += v * src[lane];
    }
    out[(size_t)wid * DIM + lane] = acc;
}

// ---------- fallback: atomic scatter SpMM (if ws too small for CSR) ----------
__global__ void spmm_scatter(const int* __restrict__ rows,
                             const int* __restrict__ cols,
                             const float* __restrict__ vals,
                             const float* __restrict__ Hu,
                             const float* __restrict__ Hi,
                             float* __restrict__ out) {
    int gid = blockIdx.x * blockDim.x + threadIdx.x;
    int e = gid >> 4;
    int s = gid & 15;
    if (e >= NNZ) return;
    int r = rows[e];
    int c = cols[e];
    float v = vals[e];
    const float* src = (c < N_USERS) ? (Hu + (size_t)c * DIM)
                                     : (Hi + (size_t)(c - N_USERS) * DIM);
    float4 x = *reinterpret_cast<const float4*>(src + s * 4);
    float* dst = out + (size_t)r * DIM + s * 4;
    atomicAdd(dst + 0, v * x.x);
    atomicAdd(dst + 1, v * x.y);
    atomicAdd(dst + 2, v * x.z);
    atomicAdd(dst + 3, v * x.w);
}

// ---------- prediction ----------
__global__ void pred_kernel(const int* __restrict__ u_idx,
                            const int* __restrict__ i_idx,
                            const float* __restrict__ U,
                            const float* __restrict__ I,
                            const float* __restrict__ bu,
                            const float* __restrict__ bi,
                            const float* __restrict__ mu,
                            float* __restrict__ out) {
    int gid = blockIdx.x * blockDim.x + threadIdx.x;
    int b = gid >> 4;
    int s = gid & 15;
    if (b >= BATCH) return;
    int u = u_idx[b];
    int it = i_idx[b];
    float4 a = *reinterpret_cast<const float4*>(U + (size_t)u * DIM + s * 4);
    float4 c = *reinterpret_cast<const float4*>(I + (size_t)it * DIM + s * 4);
    float p = a.x * c.x + a.y * c.y + a.z * c.z + a.w * c.w;
    p += __shfl_xor(p, 1);
    p += __shfl_xor(p, 2);
    p += __shfl_xor(p, 4);
    p += __shfl_xor(p, 8);
    if (s == 0) out[b] = p + bu[u] + bi[it] + mu[0];
}

extern "C" void kernel_launch(void* const* d_in, const int* in_sizes, int n_in,
                              void* d_out, int out_size, void* d_ws, size_t ws_size,
                              hipStream_t stream) {
    const int*   u_idx  = (const int*)d_in[0];
    const int*   i_idx  = (const int*)d_in[1];
    const int*   A_rows = (const int*)d_in[2];
    const int*   A_cols = (const int*)d_in[3];
    const float* A_vals = (const float*)d_in[4];
    const float* Eu     = (const float*)d_in[5];
    const float* Ei     = (const float*)d_in[6];
    const float* bu     = (const float*)d_in[7];
    const float* bi     = (const float*)d_in[8];
    const float* mu     = (const float*)d_in[9];
    float* out = (float*)d_out;

    // ---- workspace layout (4-byte units) ----
    const size_t H_ELEMS = (size_t)N_NODES * DIM;          // 9,600,000
    const size_t PTR_PAD = 150016;                          // 150001 rounded to 16B mult
    float* H1      = (float*)d_ws;
    float* H2      = H1 + H_ELEMS;
    int*   row_ptr = (int*)(H2 + H_ELEMS);
    int*   counts  = row_ptr + PTR_PAD;
    int*   cursor  = counts + PTR_PAD;
    int*   colS    = cursor + PTR_PAD;
    float* valS    = (float*)(colS + NNZ);
    int*   partials= (int*)(valS + NNZ);
    const size_t NEEDED = (2 * H_ELEMS + 3 * PTR_PAD + 2 * (size_t)NNZ + 256) * 4;

    const int edge_blocks = (NNZ + 255) / 256;
    const int pred_blocks = (BATCH * 16 + 255) / 256;

    if (ws_size >= NEEDED) {
        // ---- CSR build (structure shared by both layers) ----
        zero_ws<<<(PTR_PAD / 4 + 255) / 256, 256, 0, stream>>>((float4*)counts, PTR_PAD / 4);
        count_rows<<<edge_blocks, 256, 0, stream>>>(A_rows, counts);
        scan_chunks<<<N_CHUNKS, SCAN_CHUNK, 0, stream>>>(counts, row_ptr, partials);
        scan_partials<<<1, 256, 0, stream>>>(partials, N_CHUNKS);
        finalize_ptr<<<(N_NODES + 255) / 256, 256, 0, stream>>>(row_ptr, partials, cursor);
        scatter_edges<<<edge_blocks, 256, 0, stream>>>(A_rows, A_cols, A_vals, cursor, colS, valS);

        // ---- 2× gather SpMM ----
        const int gather_blocks = ((size_t)N_NODES * 64 + 255) / 256;
        spmm_gather<<<gather_blocks, 256, 0, stream>>>(row_ptr, colS, valS, Eu, Ei, H1);
        spmm_gather<<<gather_blocks, 256, 0, stream>>>(row_ptr, colS, valS,
                                                       H1, H1 + (size_t)N_USERS * DIM, H2);
    } else {
        // ---- fallback: atomic scatter path ----
        const int n4 = 2 * N_NODES * DIM / 4;
        zero_ws<<<(n4 + 255) / 256, 256, 0, stream>>>((float4*)d_ws, n4);
        const int spmm_blocks = (NNZ * 16 + 255) / 256;
        spmm_scatter<<<spmm_blocks, 256, 0, stream>>>(A_rows, A_cols, A_vals, Eu, Ei, H1);
        spmm_scatter<<<spmm_blocks, 256, 0, stream>>>(A_rows, A_cols, A_vals,
                                                      H1, H1 + (size_t)N_USERS * DIM, H2);
    }

    pred_kernel<<<pred_blocks, 256, 0, stream>>>(u_idx, i_idx,
                                                 H2, H2 + (size_t)N_USERS * DIM,
                                                 bu, bi, mu, out);
}

// Round 4
// 457.138 us; speedup vs baseline: 5.7218x; 1.0553x over previous
//
#include <hip/hip_runtime.h>

#define N_USERS 100000
#define N_ITEMS 50000
#define N_NODES 150000
#define NNZ 1500000
#define BATCH 1048576
#define DIM 64

#define CAP 16            // bucket capacity per row (Poisson(10) degrees)
#define OVF_MAX 65536     // overflow edge list capacity (expect ~6K)

#define SCAN_CHUNK 1024
#define N_CHUNKS ((N_NODES + SCAN_CHUNK - 1) / SCAN_CHUNK)   // 147

// ---------- generic zero (graph-capture-safe) ----------
__global__ void zero_ws(float4* __restrict__ p, int n4) {
    int i = blockIdx.x * blockDim.x + threadIdx.x;
    if (i < n4) p[i] = make_float4(0.f, 0.f, 0.f, 0.f);
}

// Zero per-row counters + the overflow counter.
__global__ void zero_cnt(int4* __restrict__ cnt4, int n4, int* __restrict__ ovf_cnt) {
    int i = blockIdx.x * blockDim.x + threadIdx.x;
    if (i < n4) cnt4[i] = make_int4(0, 0, 0, 0);
    if (i == 0) *ovf_cnt = 0;
}

// ---------- bucketed scatter: one pass, no scan ----------
__global__ void scatter_bucket(const int* __restrict__ rows,
                               const int* __restrict__ cols,
                               const float* __restrict__ vals,
                               int* __restrict__ cnt,
                               int2* __restrict__ buckets,
                               int* __restrict__ ovf_cnt,
                               int4* __restrict__ ovf) {
    int e = blockIdx.x * blockDim.x + threadIdx.x;
    if (e >= NNZ) return;
    int r = rows[e];
    int2 cv;
    cv.x = cols[e];
    cv.y = __float_as_int(vals[e]);
    int slot = atomicAdd(&cnt[r], 1);
    if (slot < CAP) {
        buckets[(size_t)r * CAP + slot] = cv;
    } else {
        int p = atomicAdd(ovf_cnt, 1);
        if (p < OVF_MAX) ovf[p] = make_int4(r, cv.x, cv.y, 0);
    }
}

// ---------- SpMM gather from buckets: one wave64 per row, lane = dim ----------
__global__ void spmm_gather_bucket(const int* __restrict__ cnt,
                                   const int2* __restrict__ buckets,
                                   const float* __restrict__ Hu,
                                   const float* __restrict__ Hi,
                                   float* __restrict__ out) {
    int wid  = (blockIdx.x * blockDim.x + threadIdx.x) >> 6;
    int lane = threadIdx.x & 63;
    if (wid >= N_NODES) return;
    int n = cnt[wid];
    if (n > CAP) n = CAP;
    int2 cv = (lane < n) ? buckets[(size_t)wid * CAP + lane] : make_int2(0, 0);
    int   c_l = cv.x;
    float v_l = __int_as_float(cv.y);
    float acc = 0.f;
    for (int k = 0; k < n; ++k) {
        int   c = __shfl(c_l, k);
        float v = __shfl(v_l, k);
        const float* src = (c < N_USERS) ? (Hu + (size_t)c * DIM)
                                         : (Hi + (size_t)(c - N_USERS) * DIM);
        acc += v * src[lane];
    }
    out[(size_t)wid * DIM + lane] = acc;
}

// Apply overflow edges (rows with degree > CAP): tiny atomic scatter into out.
__global__ void apply_ovf(const int* __restrict__ ovf_cnt,
                          const int4* __restrict__ ovf,
                          const float* __restrict__ Hu,
                          const float* __restrict__ Hi,
                          float* __restrict__ out) {
    int gid = blockIdx.x * blockDim.x + threadIdx.x;
    int e = gid >> 4;
    int s = gid & 15;
    int n = *ovf_cnt;
    if (n > OVF_MAX) n = OVF_MAX;
    if (e >= n) return;
    int4 t = ovf[e];
    int r = t.x, c = t.y;
    float v = __int_as_float(t.z);
    const float* src = (c < N_USERS) ? (Hu + (size_t)c * DIM)
                                     : (Hi + (size_t)(c - N_USERS) * DIM);
    float4 x = *reinterpret_cast<const float4*>(src + s * 4);
    float* dst = out + (size_t)r * DIM + s * 4;
    atomicAdd(dst + 0, v * x.x);
    atomicAdd(dst + 1, v * x.y);
    atomicAdd(dst + 2, v * x.z);
    atomicAdd(dst + 3, v * x.w);
}

// ---------- exact-CSR fallback path (proven in round 3) ----------
__global__ void count_rows(const int* __restrict__ rows, int* __restrict__ counts) {
    int e = blockIdx.x * blockDim.x + threadIdx.x;
    if (e < NNZ) atomicAdd(&counts[rows[e]], 1);
}

__global__ void scan_chunks(const int* __restrict__ counts,
                            int* __restrict__ row_ptr,
                            int* __restrict__ partials) {
    __shared__ int sdata[SCAN_CHUNK];
    int tid = threadIdx.x;
    int i = blockIdx.x * SCAN_CHUNK + tid;
    int x = (i < N_NODES) ? counts[i] : 0;
    sdata[tid] = x;
    __syncthreads();
    for (int off = 1; off < SCAN_CHUNK; off <<= 1) {
        int t = (tid >= off) ? sdata[tid - off] : 0;
        __syncthreads();
        sdata[tid] += t;
        __syncthreads();
    }
    int incl = sdata[tid];
    if (i < N_NODES) row_ptr[i] = incl - x;
    if (tid == SCAN_CHUNK - 1) partials[blockIdx.x] = incl;
}

__global__ void scan_partials(int* __restrict__ partials, int nb) {
    __shared__ int sdata[256];
    int tid = threadIdx.x;
    if (tid < nb) sdata[tid] = partials[tid];
    __syncthreads();
    if (tid == 0) {
        int run = 0;
        for (int b = 0; b < nb; ++b) { int t = sdata[b]; sdata[b] = run; run += t; }
    }
    __syncthreads();
    if (tid < nb) partials[tid] = sdata[tid];
}

__global__ void finalize_ptr(int* __restrict__ row_ptr,
                             const int* __restrict__ partials,
                             int* __restrict__ cursor) {
    int i = blockIdx.x * blockDim.x + threadIdx.x;
    if (i < N_NODES) {
        int p = row_ptr[i] + partials[i >> 10];
        row_ptr[i] = p;
        cursor[i] = p;
    }
    if (i == 0) row_ptr[N_NODES] = NNZ;
}

__global__ void scatter_edges(const int* __restrict__ rows,
                              const int* __restrict__ cols,
                              const float* __restrict__ vals,
                              int* __restrict__ cursor,
                              int* __restrict__ colS,
                              float* __restrict__ valS) {
    int e = blockIdx.x * blockDim.x + threadIdx.x;
    if (e >= NNZ) return;
    int r = rows[e];
    int pos = atomicAdd(&cursor[r], 1);
    colS[pos] = cols[e];
    valS[pos] = vals[e];
}

__global__ void spmm_gather(const int* __restrict__ row_ptr,
                            const int* __restrict__ colS,
                            const float* __restrict__ valS,
                            const float* __restrict__ Hu,
                            const float* __restrict__ Hi,
                            float* __restrict__ out) {
    int wid  = (blockIdx.x * blockDim.x + threadIdx.x) >> 6;
    int lane = threadIdx.x & 63;
    if (wid >= N_NODES) return;
    int beg = row_ptr[wid];
    int end = row_ptr[wid + 1];
    int n = end - beg;
    int   c_l = (lane < n) ? colS[beg + lane] : 0;
    float v_l = (lane < n) ? valS[beg + lane] : 0.f;
    float acc = 0.f;
    int nn = (n < 64) ? n : 64;
    for (int k = 0; k < nn; ++k) {
        int   c = __shfl(c_l, k);
        float v = __shfl(v_l, k);
        const float* src = (c < N_USERS) ? (Hu + (size_t)c * DIM)
                                         : (Hi + (size_t)(c - N_USERS) * DIM);
        acc += v * src[lane];
    }
    for (int k = 64; k < n; ++k) {
        int   c = colS[beg + k];
        float v = valS[beg + k];
        const float* src = (c < N_USERS) ? (Hu + (size_t)c * DIM)
                                         : (Hi + (size_t)(c - N_USERS) * DIM);
        acc += v * src[lane];
    }
    out[(size_t)wid * DIM + lane] = acc;
}

// ---------- prediction ----------
__global__ void pred_kernel(const int* __restrict__ u_idx,
                            const int* __restrict__ i_idx,
                            const float* __restrict__ U,
                            const float* __restrict__ I,
                            const float* __restrict__ bu,
                            const float* __restrict__ bi,
                            const float* __restrict__ mu,
                            float* __restrict__ out) {
    int gid = blockIdx.x * blockDim.x + threadIdx.x;
    int b = gid >> 4;
    int s = gid & 15;
    if (b >= BATCH) return;
    int u = u_idx[b];
    int it = i_idx[b];
    float4 a = *reinterpret_cast<const float4*>(U + (size_t)u * DIM + s * 4);
    float4 c = *reinterpret_cast<const float4*>(I + (size_t)it * DIM + s * 4);
    float p = a.x * c.x + a.y * c.y + a.z * c.z + a.w * c.w;
    p += __shfl_xor(p, 1);
    p += __shfl_xor(p, 2);
    p += __shfl_xor(p, 4);
    p += __shfl_xor(p, 8);
    if (s == 0) out[b] = p + bu[u] + bi[it] + mu[0];
}

extern "C" void kernel_launch(void* const* d_in, const int* in_sizes, int n_in,
                              void* d_out, int out_size, void* d_ws, size_t ws_size,
                              hipStream_t stream) {
    const int*   u_idx  = (const int*)d_in[0];
    const int*   i_idx  = (const int*)d_in[1];
    const int*   A_rows = (const int*)d_in[2];
    const int*   A_cols = (const int*)d_in[3];
    const float* A_vals = (const float*)d_in[4];
    const float* Eu     = (const float*)d_in[5];
    const float* Ei     = (const float*)d_in[6];
    const float* bu     = (const float*)d_in[7];
    const float* bi     = (const float*)d_in[8];
    const float* mu     = (const float*)d_in[9];
    float* out = (float*)d_out;

    const size_t H_ELEMS = (size_t)N_NODES * DIM;   // 9,600,000 floats
    const size_t PTR_PAD = 150016;

    const int edge_blocks = (NNZ + 255) / 256;
    const int pred_blocks = (BATCH * 16 + 255) / 256;
    const int gather_blocks = ((size_t)N_NODES * 64 + 255) / 256;

    // ---- bucket-path layout ----
    float* H1      = (float*)d_ws;
    float* H2      = H1 + H_ELEMS;
    int*   cnt     = (int*)(H2 + H_ELEMS);
    int2*  buckets = (int2*)(cnt + PTR_PAD);
    int*   ovf_cnt = (int*)(buckets + (size_t)N_NODES * CAP);
    int4*  ovf     = (int4*)(ovf_cnt + 16);
    const size_t NEEDED_B =
        (2 * H_ELEMS + PTR_PAD + 2 * (size_t)N_NODES * CAP + 16 + 4 * (size_t)OVF_MAX) * 4;

    // ---- CSR-path layout (fallback) ----
    int*   row_ptr = (int*)(H2 + H_ELEMS);
    int*   countsC = row_ptr + PTR_PAD;
    int*   cursorC = countsC + PTR_PAD;
    int*   colS    = cursorC + PTR_PAD;
    float* valS    = (float*)(colS + NNZ);
    int*   partials= (int*)(valS + NNZ);
    const size_t NEEDED_A = (2 * H_ELEMS + 3 * PTR_PAD + 2 * (size_t)NNZ + 256) * 4;

    if (ws_size >= NEEDED_B) {
        // ---- bucketed build: one pass, no count/scan ----
        zero_cnt<<<(PTR_PAD / 4 + 255) / 256, 256, 0, stream>>>((int4*)cnt, PTR_PAD / 4, ovf_cnt);
        scatter_bucket<<<edge_blocks, 256, 0, stream>>>(A_rows, A_cols, A_vals,
                                                        cnt, buckets, ovf_cnt, ovf);

        const int ovf_blocks = (OVF_MAX * 16 + 255) / 256;
        // Layer 1
        spmm_gather_bucket<<<gather_blocks, 256, 0, stream>>>(cnt, buckets, Eu, Ei, H1);
        apply_ovf<<<ovf_blocks, 256, 0, stream>>>(ovf_cnt, ovf, Eu, Ei, H1);
        // Layer 2
        spmm_gather_bucket<<<gather_blocks, 256, 0, stream>>>(cnt, buckets,
                                                              H1, H1 + (size_t)N_USERS * DIM, H2);
        apply_ovf<<<ovf_blocks, 256, 0, stream>>>(ovf_cnt, ovf,
                                                  H1, H1 + (size_t)N_USERS * DIM, H2);
    } else if (ws_size >= NEEDED_A) {
        // ---- exact CSR fallback ----
        zero_ws<<<(PTR_PAD / 4 + 255) / 256, 256, 0, stream>>>((float4*)countsC, PTR_PAD / 4);
        count_rows<<<edge_blocks, 256, 0, stream>>>(A_rows, countsC);
        scan_chunks<<<N_CHUNKS, SCAN_CHUNK, 0, stream>>>(countsC, row_ptr, partials);
        scan_partials<<<1, 256, 0, stream>>>(partials, N_CHUNKS);
        finalize_ptr<<<(N_NODES + 255) / 256, 256, 0, stream>>>(row_ptr, partials, cursorC);
        scatter_edges<<<edge_blocks, 256, 0, stream>>>(A_rows, A_cols, A_vals, cursorC, colS, valS);
        spmm_gather<<<gather_blocks, 256, 0, stream>>>(row_ptr, colS, valS, Eu, Ei, H1);
        spmm_gather<<<gather_blocks, 256, 0, stream>>>(row_ptr, colS, valS,
                                                       H1, H1 + (size_t)N_USERS * DIM, H2);
    }

    pred_kernel<<<pred_blocks, 256, 0, stream>>>(u_idx, i_idx,
                                                 H2, H2 + (size_t)N_USERS * DIM,
                                                 bu, bi, mu, out);
}

// Round 5
// 336.659 us; speedup vs baseline: 7.7694x; 1.3579x over previous
//
#include <hip/hip_runtime.h>

#define N_USERS 100000
#define N_ITEMS 50000
#define N_NODES 150000
#define NNZ 1500000
#define BATCH 1048576
#define DIM 64

#define BIN_SHIFT 9
#define BIN_ROWS 512                                   // rows per bin
#define NBINS ((N_NODES + BIN_ROWS - 1) / BIN_ROWS)    // 293
#define NROWS_PAD (NBINS * BIN_ROWS)                   // 150016
#define CAPB 8192                                      // binned capacity per bin (mean 5120, sd ~72)
#define CAPR 15                                        // bucket entries per row (128B row)
#define EPT 16
#define EPB (256 * EPT)                                // 4096 edges per block
#define P1_BLOCKS ((NNZ + EPB - 1) / EPB)              // 367
#define OVF_MAX 32768                                  // expect ~15.5K overflow edges

// ---------- zero the small control structures (graph-capture-safe) ----------
__global__ void zero_misc(int* __restrict__ bin_cursor, int* __restrict__ ovf_cnt) {
    int i = threadIdx.x;
    if (i < NBINS) bin_cursor[i] = 0;
    if (i == 0) *ovf_cnt = 0;
}

// ---------- zero H buffers (fallback path only) ----------
__global__ void zero_ws(float4* __restrict__ p, int n4) {
    int i = blockIdx.x * blockDim.x + threadIdx.x;
    if (i < n4) p[i] = make_float4(0.f, 0.f, 0.f, 0.f);
}

// ---------- pass 1: bin edges by row block (LDS histogram, chunked writes) ----------
__global__ void p1_bin(const int* __restrict__ rows,
                       const int* __restrict__ cols,
                       const float* __restrict__ vals,
                       int* __restrict__ bin_cursor,
                       int2* __restrict__ binned,
                       int* __restrict__ ovf_cnt,
                       int4* __restrict__ ovf) {
    __shared__ int h[NBINS];
    __shared__ int lcur[NBINS];
    int tid = threadIdx.x;
    for (int i = tid; i < NBINS; i += 256) { h[i] = 0; lcur[i] = 0; }
    __syncthreads();
    int base_e = blockIdx.x * EPB;
    int re[EPT]; int ce[EPT]; float ve[EPT];
#pragma unroll
    for (int k = 0; k < EPT; ++k) {
        int e = base_e + k * 256 + tid;
        if (e < NNZ) {
            re[k] = rows[e]; ce[k] = cols[e]; ve[k] = vals[e];
            atomicAdd(&h[re[k] >> BIN_SHIFT], 1);               // LDS atomic
        } else {
            re[k] = -1; ce[k] = 0; ve[k] = 0.f;
        }
    }
    __syncthreads();
    // allocate one contiguous chunk per (block, bin); h[] becomes the chunk base
    for (int i = tid; i < NBINS; i += 256) h[i] = atomicAdd(&bin_cursor[i], h[i]);
    __syncthreads();
#pragma unroll
    for (int k = 0; k < EPT; ++k) {
        if (re[k] >= 0) {
            int b = re[k] >> BIN_SHIFT;
            int off = h[b] + atomicAdd(&lcur[b], 1);            // LDS atomic
            if (off < CAPB) {
                binned[(size_t)b * CAPB + off] =
                    make_int2((ce[k] << BIN_SHIFT) | (re[k] & (BIN_ROWS - 1)),
                              __float_as_int(ve[k]));
            } else {                                             // ~never
                int p = atomicAdd(ovf_cnt, 1);
                if (p < OVF_MAX) ovf[p] = make_int4(re[k], ce[k], __float_as_int(ve[k]), 0);
            }
        }
    }
}

// ---------- pass 2: one block per bin, build 512 bucket rows in LDS ----------
// Global row format (32 ints / 128 B): [cnt, pad, c0, v0, c1, v1, ..., c14, v14]
__global__ void p2_fill(const int* __restrict__ bin_cursor,
                        const int2* __restrict__ binned,
                        int* __restrict__ buckets,
                        int* __restrict__ ovf_cnt,
                        int4* __restrict__ ovf) {
    __shared__ int  cnt_s[BIN_ROWS];                 // 2 KB
    __shared__ int2 rowbuf[BIN_ROWS * CAPR];         // 512*15*8B = 60 KB
    int bin = blockIdx.x, tid = threadIdx.x;
    for (int i = tid; i < BIN_ROWS; i += 256) cnt_s[i] = 0;
    __syncthreads();
    int n = bin_cursor[bin]; if (n > CAPB) n = CAPB;
    for (int i = tid; i < n; i += 256) {
        int2 cv = binned[(size_t)bin * CAPB + i];
        int r = cv.x & (BIN_ROWS - 1);
        int c = (int)(((unsigned)cv.x) >> BIN_SHIFT);
        int slot = atomicAdd(&cnt_s[r], 1);          // LDS atomic, random bank
        if (slot < CAPR) {
            rowbuf[r * CAPR + slot] = make_int2(c, cv.y);
        } else {
            int p = atomicAdd(ovf_cnt, 1);
            if (p < OVF_MAX) ovf[p] = make_int4(bin * BIN_ROWS + r, c, cv.y, 0);
        }
    }
    __syncthreads();
    // coalesced writeout of 512 rows x 128 B
    int* dst = buckets + (size_t)bin * BIN_ROWS * 32;
    for (int w = tid; w < BIN_ROWS * 32; w += 256) {
        int r = w >> 5, k = w & 31;
        int val;
        if (k == 0)      val = min(cnt_s[r], CAPR);
        else if (k == 1) val = 0;
        else {
            int2 t = rowbuf[r * CAPR + ((k - 2) >> 1)];
            val = (k & 1) ? t.y : t.x;
        }
        dst[w] = val;
    }
}

// ---------- SpMM gather: one wave64 per row, fully unrolled (MLP=15) ----------
__global__ void spmm_gather_b(const int* __restrict__ buckets,
                              const float* __restrict__ Hu,
                              const float* __restrict__ Hi,
                              float* __restrict__ out) {
    int gt = blockIdx.x * blockDim.x + threadIdx.x;
    int wid = gt >> 6;
    int lane = threadIdx.x & 63;
    if (wid >= N_NODES) return;
    const int2* row = (const int2*)(buckets + (size_t)wid * 32);
    int2 cv = (lane < 16) ? row[lane] : make_int2(0, 0);
    int cnt = __shfl(cv.x, 0);                       // word0 = cnt (<= 15)
    float acc = 0.f;
#pragma unroll
    for (int k = 0; k < CAPR; ++k) {
        int cs = __shfl(cv.x, k + 1);
        int vi = __shfl(cv.y, k + 1);
        bool p = (k < cnt);
        int   c = p ? cs : 0;                        // dummy -> node 0 (L1-hot)
        float v = p ? __int_as_float(vi) : 0.f;
        const float* src = (c < N_USERS) ? (Hu + (size_t)c * DIM)
                                         : (Hi + (size_t)(c - N_USERS) * DIM);
        acc += v * src[lane];
    }
    out[(size_t)wid * DIM + lane] = acc;
}

// ---------- apply overflow edges (deg > 15 tails): tiny atomic scatter ----------
__global__ void apply_ovf(const int* __restrict__ ovf_cnt,
                          const int4* __restrict__ ovf,
                          const float* __restrict__ Hu,
                          const float* __restrict__ Hi,
                          float* __restrict__ out) {
    int gid = blockIdx.x * blockDim.x + threadIdx.x;
    int e = gid >> 4;
    int s = gid & 15;
    int n = *ovf_cnt;
    if (n > OVF_MAX) n = OVF_MAX;
    if (e >= n) return;
    int4 t = ovf[e];
    int r = t.x, c = t.y;
    float v = __int_as_float(t.z);
    const float* src = (c < N_USERS) ? (Hu + (size_t)c * DIM)
                                     : (Hi + (size_t)(c - N_USERS) * DIM);
    float4 x = *reinterpret_cast<const float4*>(src + s * 4);
    float* dst = out + (size_t)r * DIM + s * 4;
    atomicAdd(dst + 0, v * x.x);
    atomicAdd(dst + 1, v * x.y);
    atomicAdd(dst + 2, v * x.z);
    atomicAdd(dst + 3, v * x.w);
}

// ---------- fallback: edge-parallel atomic scatter SpMM (ws too small) ----------
__global__ void spmm_scatter(const int* __restrict__ rows,
                             const int* __restrict__ cols,
                             const float* __restrict__ vals,
                             const float* __restrict__ Hu,
                             const float* __restrict__ Hi,
                             float* __restrict__ out) {
    int gid = blockIdx.x * blockDim.x + threadIdx.x;
    int e = gid >> 4;
    int s = gid & 15;
    if (e >= NNZ) return;
    int r = rows[e];
    int c = cols[e];
    float v = vals[e];
    const float* src = (c < N_USERS) ? (Hu + (size_t)c * DIM)
                                     : (Hi + (size_t)(c - N_USERS) * DIM);
    float4 x = *reinterpret_cast<const float4*>(src + s * 4);
    float* dst = out + (size_t)r * DIM + s * 4;
    atomicAdd(dst + 0, v * x.x);
    atomicAdd(dst + 1, v * x.y);
    atomicAdd(dst + 2, v * x.z);
    atomicAdd(dst + 3, v * x.w);
}

// ---------- prediction ----------
__global__ void pred_kernel(const int* __restrict__ u_idx,
                            const int* __restrict__ i_idx,
                            const float* __restrict__ U,
                            const float* __restrict__ I,
                            const float* __restrict__ bu,
                            const float* __restrict__ bi,
                            const float* __restrict__ mu,
                            float* __restrict__ out) {
    int gid = blockIdx.x * blockDim.x + threadIdx.x;
    int b = gid >> 4;
    int s = gid & 15;
    if (b >= BATCH) return;
    int u = u_idx[b];
    int it = i_idx[b];
    float4 a = *reinterpret_cast<const float4*>(U + (size_t)u * DIM + s * 4);
    float4 c = *reinterpret_cast<const float4*>(I + (size_t)it * DIM + s * 4);
    float p = a.x * c.x + a.y * c.y + a.z * c.z + a.w * c.w;
    p += __shfl_xor(p, 1);
    p += __shfl_xor(p, 2);
    p += __shfl_xor(p, 4);
    p += __shfl_xor(p, 8);
    if (s == 0) out[b] = p + bu[u] + bi[it] + mu[0];
}

extern "C" void kernel_launch(void* const* d_in, const int* in_sizes, int n_in,
                              void* d_out, int out_size, void* d_ws, size_t ws_size,
                              hipStream_t stream) {
    const int*   u_idx  = (const int*)d_in[0];
    const int*   i_idx  = (const int*)d_in[1];
    const int*   A_rows = (const int*)d_in[2];
    const int*   A_cols = (const int*)d_in[3];
    const float* A_vals = (const float*)d_in[4];
    const float* Eu     = (const float*)d_in[5];
    const float* Ei     = (const float*)d_in[6];
    const float* bu     = (const float*)d_in[7];
    const float* bi     = (const float*)d_in[8];
    const float* mu     = (const float*)d_in[9];
    float* out = (float*)d_out;

    const size_t H_ELEMS = (size_t)N_NODES * DIM;   // 9,600,000 floats

    // ---- workspace layout (ints) ----
    // H1 | H2 (binned aliased inside; dead before H2 written) | buckets | cursors | ovf
    float* H1         = (float*)d_ws;
    float* H2         = H1 + H_ELEMS;
    int2*  binned     = (int2*)H2;                  // NBINS*CAPB int2 = 19.2 MB <= H2
    int*   buckets    = (int*)(H2 + H_ELEMS);       // NROWS_PAD*32 ints
    int*   bin_cursor = buckets + (size_t)NROWS_PAD * 32;
    int*   ovf_cnt    = bin_cursor + 512;
    int4*  ovf        = (int4*)(ovf_cnt + 16);      // 16B-aligned
    const size_t NEEDED =
        (2 * H_ELEMS + (size_t)NROWS_PAD * 32 + 512 + 16 + 4 * (size_t)OVF_MAX) * 4;

    const int pred_blocks   = (BATCH * 16 + 255) / 256;
    const int gather_blocks = ((int)((size_t)N_NODES * 64 / 256));
    const int ovf_blocks    = (OVF_MAX * 16 + 255) / 256;

    if (ws_size >= NEEDED) {
        zero_misc<<<1, 512, 0, stream>>>(bin_cursor, ovf_cnt);
        p1_bin<<<P1_BLOCKS, 256, 0, stream>>>(A_rows, A_cols, A_vals,
                                              bin_cursor, binned, ovf_cnt, ovf);
        p2_fill<<<NBINS, 256, 0, stream>>>(bin_cursor, binned, buckets, ovf_cnt, ovf);

        // Layer 1: H1 = A @ [Eu; Ei]
        spmm_gather_b<<<gather_blocks, 256, 0, stream>>>(buckets, Eu, Ei, H1);
        apply_ovf<<<ovf_blocks, 256, 0, stream>>>(ovf_cnt, ovf, Eu, Ei, H1);
        // Layer 2: H2 = A @ H1
        spmm_gather_b<<<gather_blocks, 256, 0, stream>>>(buckets,
                                                         H1, H1 + (size_t)N_USERS * DIM, H2);
        apply_ovf<<<ovf_blocks, 256, 0, stream>>>(ovf_cnt, ovf,
                                                  H1, H1 + (size_t)N_USERS * DIM, H2);
    } else {
        // fallback: edge-parallel atomics (needs only 76.8 MB)
        const int n4 = 2 * N_NODES * DIM / 4;
        zero_ws<<<(n4 + 255) / 256, 256, 0, stream>>>((float4*)d_ws, n4);
        const int spmm_blocks = (NNZ * 16 + 255) / 256;
        spmm_scatter<<<spmm_blocks, 256, 0, stream>>>(A_rows, A_cols, A_vals, Eu, Ei, H1);
        spmm_scatter<<<spmm_blocks, 256, 0, stream>>>(A_rows, A_cols, A_vals,
                                                      H1, H1 + (size_t)N_USERS * DIM, H2);
    }

    pred_kernel<<<pred_blocks, 256, 0, stream>>>(u_idx, i_idx,
                                                 H2, H2 + (size_t)N_USERS * DIM,
                                                 bu, bi, mu, out);
}

// Round 6
// 326.554 us; speedup vs baseline: 8.0098x; 1.0309x over previous
//
#include <hip/hip_runtime.h>

#define N_USERS 100000
#define N_ITEMS 50000
#define N_NODES 150000
#define NNZ 1500000
#define BATCH 1048576
#define DIM 64

#define BIN_SHIFT 9
#define BIN_ROWS 512                                   // rows per bin
#define NBINS ((N_NODES + BIN_ROWS - 1) / BIN_ROWS)    // 293
#define NROWS_PAD (NBINS * BIN_ROWS)                   // 150016
#define CAPB 8192                                      // binned capacity per bin (mean 5120)
#define CAPR 15                                        // bucket entries per row (128B row)
#define EPT 16
#define EPB (256 * EPT)                                // 4096 edges per block
#define P1_BLOCKS ((NNZ + EPB - 1) / EPB)              // 367
#define OVF_MAX 32768                                  // expect ~12-16K overflow edges

// ---------- zero the small control structures (graph-capture-safe) ----------
__global__ void zero_misc(int* __restrict__ bin_cursor, int* __restrict__ ovf_cnt) {
    int i = threadIdx.x;
    if (i < NBINS) bin_cursor[i] = 0;
    if (i == 0) *ovf_cnt = 0;
}

// ---------- zero H buffers (fallback path only) ----------
__global__ void zero_ws(float4* __restrict__ p, int n4) {
    int i = blockIdx.x * blockDim.x + threadIdx.x;
    if (i < n4) p[i] = make_float4(0.f, 0.f, 0.f, 0.f);
}

// ---------- pass 1: bin edges by row block (LDS histogram, chunked writes) ----------
__global__ void p1_bin(const int* __restrict__ rows,
                       const int* __restrict__ cols,
                       const float* __restrict__ vals,
                       int* __restrict__ bin_cursor,
                       int2* __restrict__ binned,
                       int* __restrict__ ovf_cnt,
                       int4* __restrict__ ovf) {
    __shared__ int h[NBINS];
    __shared__ int lcur[NBINS];
    int tid = threadIdx.x;
    for (int i = tid; i < NBINS; i += 256) { h[i] = 0; lcur[i] = 0; }
    __syncthreads();
    int base_e = blockIdx.x * EPB;
    int re[EPT]; int ce[EPT]; float ve[EPT];
#pragma unroll
    for (int k = 0; k < EPT; ++k) {
        int e = base_e + k * 256 + tid;
        if (e < NNZ) {
            re[k] = rows[e]; ce[k] = cols[e]; ve[k] = vals[e];
            atomicAdd(&h[re[k] >> BIN_SHIFT], 1);               // LDS atomic
        } else {
            re[k] = -1; ce[k] = 0; ve[k] = 0.f;
        }
    }
    __syncthreads();
    // allocate one contiguous chunk per (block, bin); h[] becomes the chunk base
    for (int i = tid; i < NBINS; i += 256) h[i] = atomicAdd(&bin_cursor[i], h[i]);
    __syncthreads();
#pragma unroll
    for (int k = 0; k < EPT; ++k) {
        if (re[k] >= 0) {
            int b = re[k] >> BIN_SHIFT;
            int off = h[b] + atomicAdd(&lcur[b], 1);            // LDS atomic
            if (off < CAPB) {
                binned[(size_t)b * CAPB + off] =
                    make_int2((ce[k] << BIN_SHIFT) | (re[k] & (BIN_ROWS - 1)),
                              __float_as_int(ve[k]));
            } else {                                             // ~never
                int p = atomicAdd(ovf_cnt, 1);
                if (p < OVF_MAX) ovf[p] = make_int4(re[k], ce[k], __float_as_int(ve[k]), 0);
            }
        }
    }
}

// ---------- pass 2: one 1024-thread block per bin, build 512 bucket rows in LDS ----------
// Global row format (32 ints / 128 B): [cnt, pad, c0, v0, c1, v1, ..., c14, v14]
__global__ __launch_bounds__(1024)
void p2_fill(const int* __restrict__ bin_cursor,
             const int2* __restrict__ binned,
             int* __restrict__ buckets,
             int* __restrict__ ovf_cnt,
             int4* __restrict__ ovf) {
    __shared__ int  cnt_s[BIN_ROWS];                 // 2 KB
    __shared__ int2 rowbuf[BIN_ROWS * CAPR];         // 512*15*8B = 60 KB
    int bin = blockIdx.x, tid = threadIdx.x;
    for (int i = tid; i < BIN_ROWS; i += 1024) cnt_s[i] = 0;
    __syncthreads();
    int n = bin_cursor[bin]; if (n > CAPB) n = CAPB;
    for (int i = tid; i < n; i += 1024) {
        int2 cv = binned[(size_t)bin * CAPB + i];
        int r = cv.x & (BIN_ROWS - 1);
        int c = (int)(((unsigned)cv.x) >> BIN_SHIFT);
        int slot = atomicAdd(&cnt_s[r], 1);          // LDS atomic, random bank
        if (slot < CAPR) {
            rowbuf[r * CAPR + slot] = make_int2(c, cv.y);
        } else {
            int p = atomicAdd(ovf_cnt, 1);
            if (p < OVF_MAX) ovf[p] = make_int4(bin * BIN_ROWS + r, c, cv.y, 0);
        }
    }
    __syncthreads();
    // coalesced int4 writeout of 512 rows x 128 B  (512*8 = 4096 int4)
    int4* dst = (int4*)(buckets + (size_t)bin * BIN_ROWS * 32);
    for (int idx = tid; idx < BIN_ROWS * 8; idx += 1024) {
        int r = idx >> 3, q = idx & 7;
        int4 o;
        if (q == 0) {
            int2 t = rowbuf[r * CAPR];               // entry 0 (may be garbage if cnt==0; gated by cnt)
            o = make_int4(min(cnt_s[r], CAPR), 0, t.x, t.y);
        } else {
            int2 a = rowbuf[r * CAPR + 2 * q - 1];
            int2 b = rowbuf[r * CAPR + 2 * q];
            o = make_int4(a.x, a.y, b.x, b.y);
        }
        dst[idx] = o;
    }
}

// ---------- SpMM gather: one wave64 per row, fully unrolled (MLP=15) ----------
__global__ void spmm_gather_b(const int* __restrict__ buckets,
                              const float* __restrict__ Hu,
                              const float* __restrict__ Hi,
                              float* __restrict__ out) {
    int gt = blockIdx.x * blockDim.x + threadIdx.x;
    int wid = gt >> 6;
    int lane = threadIdx.x & 63;
    if (wid >= N_NODES) return;
    const int2* row = (const int2*)(buckets + (size_t)wid * 32);
    int2 cv = (lane < 16) ? row[lane] : make_int2(0, 0);
    int cnt = __shfl(cv.x, 0);                       // word0 = cnt (<= 15)
    float acc = 0.f;
#pragma unroll
    for (int k = 0; k < CAPR; ++k) {
        int cs = __shfl(cv.x, k + 1);
        int vi = __shfl(cv.y, k + 1);
        bool p = (k < cnt);
        int   c = p ? cs : 0;                        // dummy -> node 0 (L1-hot)
        float v = p ? __int_as_float(vi) : 0.f;
        const float* src = (c < N_USERS) ? (Hu + (size_t)c * DIM)
                                         : (Hi + (size_t)(c - N_USERS) * DIM);
        acc += v * src[lane];
    }
    out[(size_t)wid * DIM + lane] = acc;
}

// ---------- apply overflow edges (deg > 15 tails): tiny atomic scatter ----------
__global__ void apply_ovf(const int* __restrict__ ovf_cnt,
                          const int4* __restrict__ ovf,
                          const float* __restrict__ Hu,
                          const float* __restrict__ Hi,
                          float* __restrict__ out) {
    int gid = blockIdx.x * blockDim.x + threadIdx.x;
    int e = gid >> 4;
    int s = gid & 15;
    int n = *ovf_cnt;
    if (n > OVF_MAX) n = OVF_MAX;
    if (e >= n) return;
    int4 t = ovf[e];
    int r = t.x, c = t.y;
    float v = __int_as_float(t.z);
    const float* src = (c < N_USERS) ? (Hu + (size_t)c * DIM)
                                     : (Hi + (size_t)(c - N_USERS) * DIM);
    float4 x = *reinterpret_cast<const float4*>(src + s * 4);
    float* dst = out + (size_t)r * DIM + s * 4;
    atomicAdd(dst + 0, v * x.x);
    atomicAdd(dst + 1, v * x.y);
    atomicAdd(dst + 2, v * x.z);
    atomicAdd(dst + 3, v * x.w);
}

// ---------- fallback: edge-parallel atomic scatter SpMM (ws too small) ----------
__global__ void spmm_scatter(const int* __restrict__ rows,
                             const int* __restrict__ cols,
                             const float* __restrict__ vals,
                             const float* __restrict__ Hu,
                             const float* __restrict__ Hi,
                             float* __restrict__ out) {
    int gid = blockIdx.x * blockDim.x + threadIdx.x;
    int e = gid >> 4;
    int s = gid & 15;
    if (e >= NNZ) return;
    int r = rows[e];
    int c = cols[e];
    float v = vals[e];
    const float* src = (c < N_USERS) ? (Hu + (size_t)c * DIM)
                                     : (Hi + (size_t)(c - N_USERS) * DIM);
    float4 x = *reinterpret_cast<const float4*>(src + s * 4);
    float* dst = out + (size_t)r * DIM + s * 4;
    atomicAdd(dst + 0, v * x.x);
    atomicAdd(dst + 1, v * x.y);
    atomicAdd(dst + 2, v * x.z);
    atomicAdd(dst + 3, v * x.w);
}

// ---------- prediction ----------
__global__ void pred_kernel(const int* __restrict__ u_idx,
                            const int* __restrict__ i_idx,
                            const float* __restrict__ U,
                            const float* __restrict__ I,
                            const float* __restrict__ bu,
                            const float* __restrict__ bi,
                            const float* __restrict__ mu,
                            float* __restrict__ out) {
    int gid = blockIdx.x * blockDim.x + threadIdx.x;
    int b = gid >> 4;
    int s = gid & 15;
    if (b >= BATCH) return;
    int u = u_idx[b];
    int it = i_idx[b];
    float4 a = *reinterpret_cast<const float4*>(U + (size_t)u * DIM + s * 4);
    float4 c = *reinterpret_cast<const float4*>(I + (size_t)it * DIM + s * 4);
    float p = a.x * c.x + a.y * c.y + a.z * c.z + a.w * c.w;
    p += __shfl_xor(p, 1);
    p += __shfl_xor(p, 2);
    p += __shfl_xor(p, 4);
    p += __shfl_xor(p, 8);
    if (s == 0) out[b] = p + bu[u] + bi[it] + mu[0];
}

extern "C" void kernel_launch(void* const* d_in, const int* in_sizes, int n_in,
                              void* d_out, int out_size, void* d_ws, size_t ws_size,
                              hipStream_t stream) {
    const int*   u_idx  = (const int*)d_in[0];
    const int*   i_idx  = (const int*)d_in[1];
    const int*   A_rows = (const int*)d_in[2];
    const int*   A_cols = (const int*)d_in[3];
    const float* A_vals = (const float*)d_in[4];
    const float* Eu     = (const float*)d_in[5];
    const float* Ei     = (const float*)d_in[6];
    const float* bu     = (const float*)d_in[7];
    const float* bi     = (const float*)d_in[8];
    const float* mu     = (const float*)d_in[9];
    float* out = (float*)d_out;

    const size_t H_ELEMS = (size_t)N_NODES * DIM;   // 9,600,000 floats

    // ---- workspace layout (ints) ----
    // H1 | H2 (binned aliased inside; dead before H2 written) | buckets | cursors | ovf
    float* H1         = (float*)d_ws;
    float* H2         = H1 + H_ELEMS;
    int2*  binned     = (int2*)H2;                  // NBINS*CAPB int2 = 19.2 MB <= H2
    int*   buckets    = (int*)(H2 + H_ELEMS);       // NROWS_PAD*32 ints
    int*   bin_cursor = buckets + (size_t)NROWS_PAD * 32;
    int*   ovf_cnt    = bin_cursor + 512;
    int4*  ovf        = (int4*)(ovf_cnt + 16);      // 16B-aligned
    const size_t NEEDED =
        (2 * H_ELEMS + (size_t)NROWS_PAD * 32 + 512 + 16 + 4 * (size_t)OVF_MAX) * 4;

    const int pred_blocks   = (BATCH * 16 + 255) / 256;
    const int gather_blocks = ((int)((size_t)N_NODES * 64 / 256));
    const int ovf_blocks    = (OVF_MAX * 16 + 255) / 256;

    if (ws_size >= NEEDED) {
        zero_misc<<<1, 512, 0, stream>>>(bin_cursor, ovf_cnt);
        p1_bin<<<P1_BLOCKS, 256, 0, stream>>>(A_rows, A_cols, A_vals,
                                              bin_cursor, binned, ovf_cnt, ovf);
        p2_fill<<<NBINS, 1024, 0, stream>>>(bin_cursor, binned, buckets, ovf_cnt, ovf);

        // Layer 1: H1 = A @ [Eu; Ei]
        spmm_gather_b<<<gather_blocks, 256, 0, stream>>>(buckets, Eu, Ei, H1);
        apply_ovf<<<ovf_blocks, 256, 0, stream>>>(ovf_cnt, ovf, Eu, Ei, H1);
        // Layer 2: H2 = A @ H1
        spmm_gather_b<<<gather_blocks, 256, 0, stream>>>(buckets,
                                                         H1, H1 + (size_t)N_USERS * DIM, H2);
        apply_ovf<<<ovf_blocks, 256, 0, stream>>>(ovf_cnt, ovf,
                                                  H1, H1 + (size_t)N_USERS * DIM, H2);
    } else {
        // fallback: edge-parallel atomics (needs only 76.8 MB)
        const int n4 = 2 * N_NODES * DIM / 4;
        zero_ws<<<(n4 + 255) / 256, 256, 0, stream>>>((float4*)d_ws, n4);
        const int spmm_blocks = (NNZ * 16 + 255) / 256;
        spmm_scatter<<<spmm_blocks, 256, 0, stream>>>(A_rows, A_cols, A_vals, Eu, Ei, H1);
        spmm_scatter<<<spmm_blocks, 256, 0, stream>>>(A_rows, A_cols, A_vals,
                                                      H1, H1 + (size_t)N_USERS * DIM, H2);
    }

    pred_kernel<<<pred_blocks, 256, 0, stream>>>(u_idx, i_idx,
                                                 H2, H2 + (size_t)N_USERS * DIM,
                                                 bu, bi, mu, out);
}

// Round 7
// 260.180 us; speedup vs baseline: 10.0532x; 1.2551x over previous
//
#include <hip/hip_runtime.h>

#define N_USERS 100000
#define N_ITEMS 50000
#define N_NODES 150000
#define NNZ 1500000
#define BATCH 1048576
#define DIM 64

#define BIN_SHIFT 9
#define BIN_ROWS 512
#define NBINS ((N_NODES + BIN_ROWS - 1) / BIN_ROWS)    // 293
#define NROWS_PAD (NBINS * BIN_ROWS)                   // 150016
#define CAPB 8192                                      // per-bin edge capacity (mean 5120)
#define CAPR 15                                        // bucket entries per row (128B row)
#define CAPE 8                                         // ext entries per row (covers deg<=23)
#define EPT 16
#define EPB (256 * EPT)
#define P1_BLOCKS ((NNZ + EPB - 1) / EPB)              // 367
#define G_MAX 16384                                    // bin-capacity overflow list (never in practice)

typedef unsigned short ushortT;

__device__ __forceinline__ float bf2f(ushortT x) {
    return __uint_as_float(((unsigned)x) << 16);
}
__device__ __forceinline__ ushortT f2bf(float x) {      // RNE
    unsigned u = __float_as_uint(x);
    return (ushortT)((u + 0x7FFFu + ((u >> 16) & 1u)) >> 16);
}
__device__ __forceinline__ unsigned pack2(float a, float b) {
    unsigned ua = __float_as_uint(a), ub = __float_as_uint(b);
    ua = (ua + 0x7FFFu + ((ua >> 16) & 1u)) >> 16;
    ub = (ub + 0x7FFFu + ((ub >> 16) & 1u)) >> 16;
    return ua | (ub << 16);
}

// ---------- zero control structures ----------
__global__ void zero_misc(int* __restrict__ bin_cursor, int* __restrict__ g_cnt) {
    int i = threadIdx.x;
    if (i < NBINS) bin_cursor[i] = 0;
    if (i == 0) *g_cnt = 0;
}

__global__ void zero_ws(float4* __restrict__ p, int n4) {
    int i = blockIdx.x * blockDim.x + threadIdx.x;
    if (i < n4) p[i] = make_float4(0.f, 0.f, 0.f, 0.f);
}

// ---------- convert [Eu;Ei] f32 -> concatenated bf16 table ----------
__global__ void conv_E(const float4* __restrict__ Eu, const float4* __restrict__ Ei,
                       uint2* __restrict__ Eb) {
    int i = blockIdx.x * blockDim.x + threadIdx.x;
    if (i >= (N_USERS + N_ITEMS) * DIM / 4) return;
    float4 x = (i < N_USERS * DIM / 4) ? Eu[i] : Ei[i - N_USERS * DIM / 4];
    Eb[i] = make_uint2(pack2(x.x, x.y), pack2(x.z, x.w));
}

// ---------- pass 1: bin edges by row block ----------
__global__ void p1_bin(const int* __restrict__ rows,
                       const int* __restrict__ cols,
                       const float* __restrict__ vals,
                       int* __restrict__ bin_cursor,
                       int2* __restrict__ binned,
                       int* __restrict__ g_cnt,
                       int4* __restrict__ G) {
    __shared__ int h[NBINS];
    __shared__ int lcur[NBINS];
    int tid = threadIdx.x;
    for (int i = tid; i < NBINS; i += 256) { h[i] = 0; lcur[i] = 0; }
    __syncthreads();
    int base_e = blockIdx.x * EPB;
    int re[EPT]; int ce[EPT]; float ve[EPT];
#pragma unroll
    for (int k = 0; k < EPT; ++k) {
        int e = base_e + k * 256 + tid;
        if (e < NNZ) {
            re[k] = rows[e]; ce[k] = cols[e]; ve[k] = vals[e];
            atomicAdd(&h[re[k] >> BIN_SHIFT], 1);
        } else {
            re[k] = -1; ce[k] = 0; ve[k] = 0.f;
        }
    }
    __syncthreads();
    for (int i = tid; i < NBINS; i += 256) h[i] = atomicAdd(&bin_cursor[i], h[i]);
    __syncthreads();
#pragma unroll
    for (int k = 0; k < EPT; ++k) {
        if (re[k] >= 0) {
            int b = re[k] >> BIN_SHIFT;
            int off = h[b] + atomicAdd(&lcur[b], 1);
            if (off < CAPB) {
                binned[(size_t)b * CAPB + off] =
                    make_int2((ce[k] << BIN_SHIFT) | (re[k] & (BIN_ROWS - 1)),
                              __float_as_int(ve[k]));
            } else {                                     // statistically impossible; correctness path
                int p = atomicAdd(g_cnt, 1);
                if (p < G_MAX) G[p] = make_int4(re[k], ce[k], __float_as_int(ve[k]), 0);
            }
        }
    }
}

// ---------- pass 2: build 512 bucket rows (+ext) per bin in LDS ----------
// Row format (32 ints / 128 B): [cnt_full, pad, c0, v0, ..., c14, v14]
__global__ __launch_bounds__(1024)
void p2_fill(const int* __restrict__ bin_cursor,
             const int2* __restrict__ binned,
             int* __restrict__ buckets,
             int2* __restrict__ ext) {
    __shared__ int  cnt_s[BIN_ROWS];
    __shared__ int2 rowbuf[BIN_ROWS * CAPR];             // 60 KB
    int bin = blockIdx.x, tid = threadIdx.x;
    for (int i = tid; i < BIN_ROWS; i += 1024) cnt_s[i] = 0;
    __syncthreads();
    int n = bin_cursor[bin]; if (n > CAPB) n = CAPB;
    for (int i = tid; i < n; i += 1024) {
        int2 cv = binned[(size_t)bin * CAPB + i];
        int r = cv.x & (BIN_ROWS - 1);
        int c = (int)(((unsigned)cv.x) >> BIN_SHIFT);
        int slot = atomicAdd(&cnt_s[r], 1);
        if (slot < CAPR) {
            rowbuf[r * CAPR + slot] = make_int2(c, cv.y);
        } else if (slot < CAPR + CAPE) {
            ext[(size_t)(bin * BIN_ROWS + r) * CAPE + (slot - CAPR)] = make_int2(c, cv.y);
        }
        // slot >= CAPR+CAPE: dropped; gather recomputes that row via bin scan
    }
    __syncthreads();
    int4* dst = (int4*)(buckets + (size_t)bin * BIN_ROWS * 32);
    for (int idx = tid; idx < BIN_ROWS * 8; idx += 1024) {
        int r = idx >> 3, q = idx & 7;
        int4 o;
        if (q == 0) {
            int2 t = rowbuf[r * CAPR];
            o = make_int4(cnt_s[r], 0, t.x, t.y);        // full count (may exceed CAPR)
        } else {
            int2 a = rowbuf[r * CAPR + 2 * q - 1];
            int2 b = rowbuf[r * CAPR + 2 * q];
            o = make_int4(a.x, a.y, b.x, b.y);
        }
        dst[idx] = o;
    }
}

// ---------- SpMM gather (bf16 features in, bf16 out): one wave64 per row ----------
__global__ void spmm_gather16(const int* __restrict__ buckets,
                              const int2* __restrict__ ext,
                              const int* __restrict__ bin_cursor,
                              const int2* __restrict__ binned,
                              const int* __restrict__ g_cnt,
                              const int4* __restrict__ G,
                              const ushortT* __restrict__ F,
                              ushortT* __restrict__ out) {
    int gt = blockIdx.x * blockDim.x + threadIdx.x;
    int wid = gt >> 6;
    int lane = threadIdx.x & 63;
    if (wid >= N_NODES) return;
    const int2* row = (const int2*)(buckets + (size_t)wid * 32);
    int2 cv = (lane < 16) ? row[lane] : make_int2(0, 0);
    int cnt = __shfl(cv.x, 0);
    float acc = 0.f;
    if (cnt <= CAPR + CAPE) {
        int nb = (cnt < CAPR) ? cnt : CAPR;
#pragma unroll
        for (int k = 0; k < CAPR; ++k) {
            int cs = __shfl(cv.x, k + 1);
            int vi = __shfl(cv.y, k + 1);
            bool p = (k < nb);
            int   c = p ? cs : 0;
            float v = p ? __int_as_float(vi) : 0.f;
            acc += v * bf2f(F[(size_t)c * DIM + lane]);
        }
        if (cnt > CAPR) {
            int ne = cnt - CAPR;                          // <= CAPE
            int2 ev = (lane < ne) ? ext[(size_t)wid * CAPE + lane] : make_int2(0, 0);
#pragma unroll
            for (int k = 0; k < CAPE; ++k) {
                int cs = __shfl(ev.x, k);
                int vi = __shfl(ev.y, k);
                bool p = (k < ne);
                int   c = p ? cs : 0;
                float v = p ? __int_as_float(vi) : 0.f;
                acc += v * bf2f(F[(size_t)c * DIM + lane]);
            }
        }
    } else {
        // deg > 23 (P~1.6e-7/row): recompute from the bin's edge list, ballot-compacted
        int bin = wid >> BIN_SHIFT, rloc = wid & (BIN_ROWS - 1);
        int n = bin_cursor[bin]; if (n > CAPB) n = CAPB;
        size_t bb = (size_t)bin * CAPB;
        for (int base = 0; base < n; base += 64) {
            int i = base + lane;
            int2 e = (i < n) ? binned[bb + i] : make_int2(0, 0);
            bool m = (i < n) && ((e.x & (BIN_ROWS - 1)) == rloc);
            unsigned long long mask = __ballot(m);
            while (mask) {
                int src = __ffsll(mask) - 1;
                mask &= mask - 1;
                int ex = __shfl(e.x, src);
                int ev2 = __shfl(e.y, src);
                int c = (int)(((unsigned)ex) >> BIN_SHIFT);
                acc += __int_as_float(ev2) * bf2f(F[(size_t)c * DIM + lane]);
            }
        }
    }
    int gc = *g_cnt;                                      // 0 in practice
    if (gc > 0) {
        if (gc > G_MAX) gc = G_MAX;
        for (int i = 0; i < gc; ++i) {
            int4 t = G[i];
            if (t.x == wid)
                acc += __int_as_float(t.z) * bf2f(F[(size_t)t.y * DIM + lane]);
        }
    }
    out[(size_t)wid * DIM + lane] = f2bf(acc);
}

// ---------- prediction (bf16 feature rows) ----------
__global__ void pred_bf16(const int* __restrict__ u_idx,
                          const int* __restrict__ i_idx,
                          const ushortT* __restrict__ F,
                          const float* __restrict__ bu,
                          const float* __restrict__ bi,
                          const float* __restrict__ mu,
                          float* __restrict__ out) {
    int gid = blockIdx.x * blockDim.x + threadIdx.x;
    int b = gid >> 4;
    int s = gid & 15;
    if (b >= BATCH) return;
    int u = u_idx[b];
    int it = i_idx[b];
    ushort4 a = *((const ushort4*)(F + (size_t)u * DIM) + s);
    ushort4 c = *((const ushort4*)(F + (size_t)(N_USERS + it) * DIM) + s);
    float p = bf2f(a.x) * bf2f(c.x) + bf2f(a.y) * bf2f(c.y)
            + bf2f(a.z) * bf2f(c.z) + bf2f(a.w) * bf2f(c.w);
    p += __shfl_xor(p, 1);
    p += __shfl_xor(p, 2);
    p += __shfl_xor(p, 4);
    p += __shfl_xor(p, 8);
    if (s == 0) out[b] = p + bu[u] + bi[it] + mu[0];
}

// ---------- f32 fallback (ws too small): edge-parallel atomics ----------
__global__ void spmm_scatter(const int* __restrict__ rows,
                             const int* __restrict__ cols,
                             const float* __restrict__ vals,
                             const float* __restrict__ Hu,
                             const float* __restrict__ Hi,
                             float* __restrict__ out) {
    int gid = blockIdx.x * blockDim.x + threadIdx.x;
    int e = gid >> 4;
    int s = gid & 15;
    if (e >= NNZ) return;
    int r = rows[e];
    int c = cols[e];
    float v = vals[e];
    const float* src = (c < N_USERS) ? (Hu + (size_t)c * DIM)
                                     : (Hi + (size_t)(c - N_USERS) * DIM);
    float4 x = *reinterpret_cast<const float4*>(src + s * 4);
    float* dst = out + (size_t)r * DIM + s * 4;
    atomicAdd(dst + 0, v * x.x);
    atomicAdd(dst + 1, v * x.y);
    atomicAdd(dst + 2, v * x.z);
    atomicAdd(dst + 3, v * x.w);
}

__global__ void pred_f32(const int* __restrict__ u_idx,
                         const int* __restrict__ i_idx,
                         const float* __restrict__ U,
                         const float* __restrict__ I,
                         const float* __restrict__ bu,
                         const float* __restrict__ bi,
                         const float* __restrict__ mu,
                         float* __restrict__ out) {
    int gid = blockIdx.x * blockDim.x + threadIdx.x;
    int b = gid >> 4;
    int s = gid & 15;
    if (b >= BATCH) return;
    int u = u_idx[b];
    int it = i_idx[b];
    float4 a = *reinterpret_cast<const float4*>(U + (size_t)u * DIM + s * 4);
    float4 c = *reinterpret_cast<const float4*>(I + (size_t)it * DIM + s * 4);
    float p = a.x * c.x + a.y * c.y + a.z * c.z + a.w * c.w;
    p += __shfl_xor(p, 1);
    p += __shfl_xor(p, 2);
    p += __shfl_xor(p, 4);
    p += __shfl_xor(p, 8);
    if (s == 0) out[b] = p + bu[u] + bi[it] + mu[0];
}

extern "C" void kernel_launch(void* const* d_in, const int* in_sizes, int n_in,
                              void* d_out, int out_size, void* d_ws, size_t ws_size,
                              hipStream_t stream) {
    const int*   u_idx  = (const int*)d_in[0];
    const int*   i_idx  = (const int*)d_in[1];
    const int*   A_rows = (const int*)d_in[2];
    const int*   A_cols = (const int*)d_in[3];
    const float* A_vals = (const float*)d_in[4];
    const float* Eu     = (const float*)d_in[5];
    const float* Ei     = (const float*)d_in[6];
    const float* bu     = (const float*)d_in[7];
    const float* bi     = (const float*)d_in[8];
    const float* mu     = (const float*)d_in[9];
    float* out = (float*)d_out;

    // ---- bf16-path workspace layout (bytes) ----
    char* ws = (char*)d_ws;
    ushortT* H1b       = (ushortT*)(ws);                    // 19,200,000 B
    ushortT* EbH2b     = (ushortT*)(ws + 19200000);         // 19,200,000 B (Eb, then H2b)
    int*     buckets   = (int*)    (ws + 38400000);         // 19,202,048 B
    int2*    binned    = (int2*)   (ws + 57602048);         // 19,202,048 B
    int2*    ext       = (int2*)   (ws + 76804096);         //  9,601,024 B
    int*     bin_cursor= (int*)    (ws + 86405120);         //      2,048 B
    int*     g_cnt     = (int*)    (ws + 86407168);         //         64 B
    int4*    G         = (int4*)   (ws + 86407232);         //    262,144 B
    const size_t NEEDED = 86407232 + (size_t)G_MAX * 16;    // 86,669,376 B

    const int pred_blocks   = (BATCH * 16 + 255) / 256;
    const int gather_blocks = (N_NODES * 64) / 256;         // 37500
    const int conv_blocks   = ((N_USERS + N_ITEMS) * DIM / 4 + 255) / 256;

    if (ws_size >= NEEDED) {
        zero_misc<<<1, 512, 0, stream>>>(bin_cursor, g_cnt);
        conv_E<<<conv_blocks, 256, 0, stream>>>((const float4*)Eu, (const float4*)Ei,
                                                (uint2*)EbH2b);
        p1_bin<<<P1_BLOCKS, 256, 0, stream>>>(A_rows, A_cols, A_vals,
                                              bin_cursor, binned, g_cnt, G);
        p2_fill<<<NBINS, 1024, 0, stream>>>(bin_cursor, binned, buckets, ext);

        // Layer 1: H1b = A @ Eb
        spmm_gather16<<<gather_blocks, 256, 0, stream>>>(buckets, ext, bin_cursor, binned,
                                                         g_cnt, G, EbH2b, H1b);
        // Layer 2: H2b = A @ H1b  (H2b overwrites Eb, dead after layer 1)
        spmm_gather16<<<gather_blocks, 256, 0, stream>>>(buckets, ext, bin_cursor, binned,
                                                         g_cnt, G, H1b, EbH2b);

        pred_bf16<<<pred_blocks, 256, 0, stream>>>(u_idx, i_idx, EbH2b, bu, bi, mu, out);
    } else {
        // f32 fallback: edge-parallel atomics (needs 76.8 MB)
        float* H1 = (float*)d_ws;
        float* H2 = H1 + (size_t)N_NODES * DIM;
        const int n4 = 2 * N_NODES * DIM / 4;
        zero_ws<<<(n4 + 255) / 256, 256, 0, stream>>>((float4*)d_ws, n4);
        const int spmm_blocks = (NNZ * 16 + 255) / 256;
        spmm_scatter<<<spmm_blocks, 256, 0, stream>>>(A_rows, A_cols, A_vals, Eu, Ei, H1);
        spmm_scatter<<<spmm_blocks, 256, 0, stream>>>(A_rows, A_cols, A_vals,
                                                      H1, H1 + (size_t)N_USERS * DIM, H2);
        pred_f32<<<pred_blocks, 256, 0, stream>>>(u_idx, i_idx,
                                                  H2, H2 + (size_t)N_USERS * DIM,
                                                  bu, bi, mu, out);
    }
}

// Round 8
// 246.348 us; speedup vs baseline: 10.6176x; 1.0561x over previous
//
#include <hip/hip_runtime.h>

#define N_USERS 100000
#define N_ITEMS 50000
#define N_NODES 150000
#define NNZ 1500000
#define BATCH 1048576
#define DIM 64

#define BIN_SHIFT 9
#define BIN_ROWS 512
#define NBINS ((N_NODES + BIN_ROWS - 1) / BIN_ROWS)    // 293
#define NROWS_PAD (NBINS * BIN_ROWS)                   // 150016
#define CAPB 8192                                      // per-bin edge capacity (mean 5120)
#define CAPR 15                                        // bucket entries per row (128B row)
#define CAPE 8                                         // ext entries per row (covers deg<=23)
#define EPT 16
#define EPB (256 * EPT)
#define P1_BLOCKS ((NNZ + EPB - 1) / EPB)              // 367
#define G_MAX 16384                                    // bin-capacity overflow list (never in practice)

typedef unsigned short ushortT;

__device__ __forceinline__ float bf2f(ushortT x) {
    return __uint_as_float(((unsigned)x) << 16);
}
__device__ __forceinline__ ushortT f2bf(float x) {      // RNE
    unsigned u = __float_as_uint(x);
    return (ushortT)((u + 0x7FFFu + ((u >> 16) & 1u)) >> 16);
}
__device__ __forceinline__ unsigned pack2(float a, float b) {
    unsigned ua = __float_as_uint(a), ub = __float_as_uint(b);
    ua = (ua + 0x7FFFu + ((ua >> 16) & 1u)) >> 16;
    ub = (ub + 0x7FFFu + ((ub >> 16) & 1u)) >> 16;
    return ua | (ub << 16);
}

// ---------- zero control structures ----------
__global__ void zero_misc(int* __restrict__ bin_cursor, int* __restrict__ g_cnt) {
    int i = threadIdx.x;
    if (i < NBINS) bin_cursor[i] = 0;
    if (i == 0) *g_cnt = 0;
}

__global__ void zero_ws(float4* __restrict__ p, int n4) {
    int i = blockIdx.x * blockDim.x + threadIdx.x;
    if (i < n4) p[i] = make_float4(0.f, 0.f, 0.f, 0.f);
}

// ---------- convert [Eu;Ei] f32 -> concatenated bf16 table ----------
__global__ void conv_E(const float4* __restrict__ Eu, const float4* __restrict__ Ei,
                       uint2* __restrict__ Eb) {
    int i = blockIdx.x * blockDim.x + threadIdx.x;
    if (i >= (N_USERS + N_ITEMS) * DIM / 4) return;
    float4 x = (i < N_USERS * DIM / 4) ? Eu[i] : Ei[i - N_USERS * DIM / 4];
    Eb[i] = make_uint2(pack2(x.x, x.y), pack2(x.z, x.w));
}

// ---------- pass 1: bin edges by row block ----------
__global__ void p1_bin(const int* __restrict__ rows,
                       const int* __restrict__ cols,
                       const float* __restrict__ vals,
                       int* __restrict__ bin_cursor,
                       int2* __restrict__ binned,
                       int* __restrict__ g_cnt,
                       int4* __restrict__ G) {
    __shared__ int h[NBINS];
    __shared__ int lcur[NBINS];
    int tid = threadIdx.x;
    for (int i = tid; i < NBINS; i += 256) { h[i] = 0; lcur[i] = 0; }
    __syncthreads();
    int base_e = blockIdx.x * EPB;
    int re[EPT]; int ce[EPT]; float ve[EPT];
#pragma unroll
    for (int k = 0; k < EPT; ++k) {
        int e = base_e + k * 256 + tid;
        if (e < NNZ) {
            re[k] = rows[e]; ce[k] = cols[e]; ve[k] = vals[e];
            atomicAdd(&h[re[k] >> BIN_SHIFT], 1);
        } else {
            re[k] = -1; ce[k] = 0; ve[k] = 0.f;
        }
    }
    __syncthreads();
    for (int i = tid; i < NBINS; i += 256) h[i] = atomicAdd(&bin_cursor[i], h[i]);
    __syncthreads();
#pragma unroll
    for (int k = 0; k < EPT; ++k) {
        if (re[k] >= 0) {
            int b = re[k] >> BIN_SHIFT;
            int off = h[b] + atomicAdd(&lcur[b], 1);
            if (off < CAPB) {
                binned[(size_t)b * CAPB + off] =
                    make_int2((ce[k] << BIN_SHIFT) | (re[k] & (BIN_ROWS - 1)),
                              __float_as_int(ve[k]));
            } else {                                     // statistically impossible; correctness path
                int p = atomicAdd(g_cnt, 1);
                if (p < G_MAX) G[p] = make_int4(re[k], ce[k], __float_as_int(ve[k]), 0);
            }
        }
    }
}

// ---------- pass 2: build 512 bucket rows (+ext) per bin in LDS ----------
// Row format (32 ints / 128 B): [cnt_full, pad, c0, v0, ..., c14, v14]
__global__ __launch_bounds__(1024)
void p2_fill(const int* __restrict__ bin_cursor,
             const int2* __restrict__ binned,
             int* __restrict__ buckets,
             int2* __restrict__ ext) {
    __shared__ int  cnt_s[BIN_ROWS];
    __shared__ int2 rowbuf[BIN_ROWS * CAPR];             // 60 KB
    int bin = blockIdx.x, tid = threadIdx.x;
    for (int i = tid; i < BIN_ROWS; i += 1024) cnt_s[i] = 0;
    __syncthreads();
    int n = bin_cursor[bin]; if (n > CAPB) n = CAPB;
    for (int i = tid; i < n; i += 1024) {
        int2 cv = binned[(size_t)bin * CAPB + i];
        int r = cv.x & (BIN_ROWS - 1);
        int c = (int)(((unsigned)cv.x) >> BIN_SHIFT);
        int slot = atomicAdd(&cnt_s[r], 1);
        if (slot < CAPR) {
            rowbuf[r * CAPR + slot] = make_int2(c, cv.y);
        } else if (slot < CAPR + CAPE) {
            ext[(size_t)(bin * BIN_ROWS + r) * CAPE + (slot - CAPR)] = make_int2(c, cv.y);
        }
        // slot >= CAPR+CAPE: dropped; gather recomputes that row via bin scan
    }
    __syncthreads();
    int4* dst = (int4*)(buckets + (size_t)bin * BIN_ROWS * 32);
    for (int idx = tid; idx < BIN_ROWS * 8; idx += 1024) {
        int r = idx >> 3, q = idx & 7;
        int4 o;
        if (q == 0) {
            int2 t = rowbuf[r * CAPR];
            o = make_int4(cnt_s[r], 0, t.x, t.y);        // full count (may exceed CAPR)
        } else {
            int2 a = rowbuf[r * CAPR + 2 * q - 1];
            int2 b = rowbuf[r * CAPR + 2 * q];
            o = make_int4(a.x, a.y, b.x, b.y);
        }
        dst[idx] = o;
    }
}

// ---------- SpMM gather (bf16): one wave64 per row, scalarized edge broadcast ----------
__global__ void spmm_gather16(const int* __restrict__ buckets,
                              const int2* __restrict__ ext,
                              const int* __restrict__ bin_cursor,
                              const int2* __restrict__ binned,
                              const int* __restrict__ g_cnt,
                              const int4* __restrict__ G,
                              const ushortT* __restrict__ F,
                              ushortT* __restrict__ out) {
    int gt = blockIdx.x * blockDim.x + threadIdx.x;
    int wid = gt >> 6;
    int lane = threadIdx.x & 63;
    if (wid >= N_NODES) return;
    const int2* row = (const int2*)(buckets + (size_t)wid * 32);
    int2 cv = (lane < 16) ? row[lane] : make_int2(0, 0);
    int cnt = __builtin_amdgcn_readlane(cv.x, 0);        // SGPR, wave-uniform
    float acc = 0.f;
    if (cnt <= CAPR + CAPE) {
        int nb = (cnt < CAPR) ? cnt : CAPR;              // scalar
#pragma unroll
        for (int k = 0; k < CAPR; ++k) {
            int cs = __builtin_amdgcn_readlane(cv.x, k + 1);   // SGPR
            int vi = __builtin_amdgcn_readlane(cv.y, k + 1);   // SGPR
            int   c = (k < nb) ? cs : 0;                 // scalar cselect; dummy -> row 0 (L1-hot)
            float v = (k < nb) ? __int_as_float(vi) : 0.f;
            const ushortT* p = F + ((size_t)c << 6);     // SGPR base -> saddr load
            acc += v * bf2f(p[lane]);
        }
        if (cnt > CAPR) {
            int ne = cnt - CAPR;                          // <= CAPE, scalar
            int2 ev = (lane < CAPE) ? ext[(size_t)wid * CAPE + lane] : make_int2(0, 0);
#pragma unroll
            for (int k = 0; k < CAPE; ++k) {
                int cs = __builtin_amdgcn_readlane(ev.x, k);
                int vi = __builtin_amdgcn_readlane(ev.y, k);
                int   c = (k < ne) ? cs : 0;
                float v = (k < ne) ? __int_as_float(vi) : 0.f;
                const ushortT* p = F + ((size_t)c << 6);
                acc += v * bf2f(p[lane]);
            }
        }
    } else {
        // deg > 23 (P~1.6e-7/row): recompute from the bin's edge list, ballot-compacted
        int bin = wid >> BIN_SHIFT, rloc = wid & (BIN_ROWS - 1);
        int n = bin_cursor[bin]; if (n > CAPB) n = CAPB;
        size_t bb = (size_t)bin * CAPB;
        for (int base = 0; base < n; base += 64) {
            int i = base + lane;
            int2 e = (i < n) ? binned[bb + i] : make_int2(0, 0);
            bool m = (i < n) && ((e.x & (BIN_ROWS - 1)) == rloc);
            unsigned long long mask = __ballot(m);
            while (mask) {
                int src = __ffsll(mask) - 1;
                mask &= mask - 1;
                int ex = __shfl(e.x, src);
                int ev2 = __shfl(e.y, src);
                int c = (int)(((unsigned)ex) >> BIN_SHIFT);
                acc += __int_as_float(ev2) * bf2f(F[(size_t)c * DIM + lane]);
            }
        }
    }
    int gc = *g_cnt;                                      // 0 in practice
    if (gc > 0) {
        if (gc > G_MAX) gc = G_MAX;
        for (int i = 0; i < gc; ++i) {
            int4 t = G[i];
            if (t.x == wid)
                acc += __int_as_float(t.z) * bf2f(F[(size_t)t.y * DIM + lane]);
        }
    }
    out[(size_t)wid * DIM + lane] = f2bf(acc);
}

// ---------- prediction (bf16 feature rows) ----------
__global__ void pred_bf16(const int* __restrict__ u_idx,
                          const int* __restrict__ i_idx,
                          const ushortT* __restrict__ F,
                          const float* __restrict__ bu,
                          const float* __restrict__ bi,
                          const float* __restrict__ mu,
                          float* __restrict__ out) {
    int gid = blockIdx.x * blockDim.x + threadIdx.x;
    int b = gid >> 4;
    int s = gid & 15;
    if (b >= BATCH) return;
    int u = u_idx[b];
    int it = i_idx[b];
    ushort4 a = *((const ushort4*)(F + (size_t)u * DIM) + s);
    ushort4 c = *((const ushort4*)(F + (size_t)(N_USERS + it) * DIM) + s);
    float p = bf2f(a.x) * bf2f(c.x) + bf2f(a.y) * bf2f(c.y)
            + bf2f(a.z) * bf2f(c.z) + bf2f(a.w) * bf2f(c.w);
    p += __shfl_xor(p, 1);
    p += __shfl_xor(p, 2);
    p += __shfl_xor(p, 4);
    p += __shfl_xor(p, 8);
    if (s == 0) out[b] = p + bu[u] + bi[it] + mu[0];
}

// ---------- f32 fallback (ws too small): edge-parallel atomics ----------
__global__ void spmm_scatter(const int* __restrict__ rows,
                             const int* __restrict__ cols,
                             const float* __restrict__ vals,
                             const float* __restrict__ Hu,
                             const float* __restrict__ Hi,
                             float* __restrict__ out) {
    int gid = blockIdx.x * blockDim.x + threadIdx.x;
    int e = gid >> 4;
    int s = gid & 15;
    if (e >= NNZ) return;
    int r = rows[e];
    int c = cols[e];
    float v = vals[e];
    const float* src = (c < N_USERS) ? (Hu + (size_t)c * DIM)
                                     : (Hi + (size_t)(c - N_USERS) * DIM);
    float4 x = *reinterpret_cast<const float4*>(src + s * 4);
    float* dst = out + (size_t)r * DIM + s * 4;
    atomicAdd(dst + 0, v * x.x);
    atomicAdd(dst + 1, v * x.y);
    atomicAdd(dst + 2, v * x.z);
    atomicAdd(dst + 3, v * x.w);
}

__global__ void pred_f32(const int* __restrict__ u_idx,
                         const int* __restrict__ i_idx,
                         const float* __restrict__ U,
                         const float* __restrict__ I,
                         const float* __restrict__ bu,
                         const float* __restrict__ bi,
                         const float* __restrict__ mu,
                         float* __restrict__ out) {
    int gid = blockIdx.x * blockDim.x + threadIdx.x;
    int b = gid >> 4;
    int s = gid & 15;
    if (b >= BATCH) return;
    int u = u_idx[b];
    int it = i_idx[b];
    float4 a = *reinterpret_cast<const float4*>(U + (size_t)u * DIM + s * 4);
    float4 c = *reinterpret_cast<const float4*>(I + (size_t)it * DIM + s * 4);
    float p = a.x * c.x + a.y * c.y + a.z * c.z + a.w * c.w;
    p += __shfl_xor(p, 1);
    p += __shfl_xor(p, 2);
    p += __shfl_xor(p, 4);
    p += __shfl_xor(p, 8);
    if (s == 0) out[b] = p + bu[u] + bi[it] + mu[0];
}

extern "C" void kernel_launch(void* const* d_in, const int* in_sizes, int n_in,
                              void* d_out, int out_size, void* d_ws, size_t ws_size,
                              hipStream_t stream) {
    const int*   u_idx  = (const int*)d_in[0];
    const int*   i_idx  = (const int*)d_in[1];
    const int*   A_rows = (const int*)d_in[2];
    const int*   A_cols = (const int*)d_in[3];
    const float* A_vals = (const float*)d_in[4];
    const float* Eu     = (const float*)d_in[5];
    const float* Ei     = (const float*)d_in[6];
    const float* bu     = (const float*)d_in[7];
    const float* bi     = (const float*)d_in[8];
    const float* mu     = (const float*)d_in[9];
    float* out = (float*)d_out;

    // ---- bf16-path workspace layout (bytes) ----
    char* ws = (char*)d_ws;
    ushortT* H1b       = (ushortT*)(ws);                    // 19,200,000 B
    ushortT* EbH2b     = (ushortT*)(ws + 19200000);         // 19,200,000 B (Eb, then H2b)
    int*     buckets   = (int*)    (ws + 38400000);         // 19,202,048 B
    int2*    binned    = (int2*)   (ws + 57602048);         // 19,202,048 B
    int2*    ext       = (int2*)   (ws + 76804096);         //  9,601,024 B
    int*     bin_cursor= (int*)    (ws + 86405120);         //      2,048 B
    int*     g_cnt     = (int*)    (ws + 86407168);         //         64 B
    int4*    G         = (int4*)   (ws + 86407232);         //    262,144 B
    const size_t NEEDED = 86407232 + (size_t)G_MAX * 16;    // 86,669,376 B

    const int pred_blocks   = (BATCH * 16 + 255) / 256;
    const int gather_blocks = (N_NODES * 64) / 256;         // 37500
    const int conv_blocks   = ((N_USERS + N_ITEMS) * DIM / 4 + 255) / 256;

    if (ws_size >= NEEDED) {
        zero_misc<<<1, 512, 0, stream>>>(bin_cursor, g_cnt);
        conv_E<<<conv_blocks, 256, 0, stream>>>((const float4*)Eu, (const float4*)Ei,
                                                (uint2*)EbH2b);
        p1_bin<<<P1_BLOCKS, 256, 0, stream>>>(A_rows, A_cols, A_vals,
                                              bin_cursor, binned, g_cnt, G);
        p2_fill<<<NBINS, 1024, 0, stream>>>(bin_cursor, binned, buckets, ext);

        // Layer 1: H1b = A @ Eb
        spmm_gather16<<<gather_blocks, 256, 0, stream>>>(buckets, ext, bin_cursor, binned,
                                                         g_cnt, G, EbH2b, H1b);
        // Layer 2: H2b = A @ H1b  (H2b overwrites Eb, dead after layer 1)
        spmm_gather16<<<gather_blocks, 256, 0, stream>>>(buckets, ext, bin_cursor, binned,
                                                         g_cnt, G, H1b, EbH2b);

        pred_bf16<<<pred_blocks, 256, 0, stream>>>(u_idx, i_idx, EbH2b, bu, bi, mu, out);
    } else {
        // f32 fallback: edge-parallel atomics (needs 76.8 MB)
        float* H1 = (float*)d_ws;
        float* H2 = H1 + (size_t)N_NODES * DIM;
        const int n4 = 2 * N_NODES * DIM / 4;
        zero_ws<<<(n4 + 255) / 256, 256, 0, stream>>>((float4*)d_ws, n4);
        const int spmm_blocks = (NNZ * 16 + 255) / 256;
        spmm_scatter<<<spmm_blocks, 256, 0, stream>>>(A_rows, A_cols, A_vals, Eu, Ei, H1);
        spmm_scatter<<<spmm_blocks, 256, 0, stream>>>(A_rows, A_cols, A_vals,
                                                      H1, H1 + (size_t)N_USERS * DIM, H2);
        pred_f32<<<pred_blocks, 256, 0, stream>>>(u_idx, i_idx,
                                                  H2, H2 + (size_t)N_USERS * DIM,
                                                  bu, bi, mu, out);
    }
}

// Round 9
// 226.524 us; speedup vs baseline: 11.5468x; 1.0875x over previous
//
#include <hip/hip_runtime.h>

#define N_USERS 100000
#define N_ITEMS 50000
#define N_NODES 150000
#define NNZ 1500000
#define BATCH 1048576
#define DIM 64

#define BIN_SHIFT 9
#define BIN_ROWS 512
#define NBINS ((N_NODES + BIN_ROWS - 1) / BIN_ROWS)    // 293
#define NROWS_PAD (NBINS * BIN_ROWS)                   // 150016
#define CAPB 8192                                      // per-bin edge capacity (mean 5120)
#define CAPR 15                                        // bucket entries per row (128B row)
#define CAPE 8                                         // ext entries per row (covers deg<=23)
#define EPT 16
#define EPB (256 * EPT)
#define P1_BLOCKS ((NNZ + EPB - 1) / EPB)              // 367
#define G_MAX 16384                                    // bin-capacity overflow list (never in practice)

typedef unsigned short ushortT;

__device__ __forceinline__ float bf2f(ushortT x) {
    return __uint_as_float(((unsigned)x) << 16);
}
__device__ __forceinline__ ushortT f2bf(float x) {      // RNE
    unsigned u = __float_as_uint(x);
    return (ushortT)((u + 0x7FFFu + ((u >> 16) & 1u)) >> 16);
}
__device__ __forceinline__ unsigned pack2(float a, float b) {
    unsigned ua = __float_as_uint(a), ub = __float_as_uint(b);
    ua = (ua + 0x7FFFu + ((ua >> 16) & 1u)) >> 16;
    ub = (ub + 0x7FFFu + ((ub >> 16) & 1u)) >> 16;
    return ua | (ub << 16);
}

// ---------- zero control structures ----------
__global__ void zero_misc(int* __restrict__ bin_cursor, int* __restrict__ g_cnt) {
    int i = threadIdx.x;
    if (i < NBINS) bin_cursor[i] = 0;
    if (i == 0) *g_cnt = 0;
}

__global__ void zero_ws(float4* __restrict__ p, int n4) {
    int i = blockIdx.x * blockDim.x + threadIdx.x;
    if (i < n4) p[i] = make_float4(0.f, 0.f, 0.f, 0.f);
}

// ---------- convert [Eu;Ei] f32 -> concatenated bf16 table ----------
__global__ void conv_E(const float4* __restrict__ Eu, const float4* __restrict__ Ei,
                       uint2* __restrict__ Eb) {
    int i = blockIdx.x * blockDim.x + threadIdx.x;
    if (i >= (N_USERS + N_ITEMS) * DIM / 4) return;
    float4 x = (i < N_USERS * DIM / 4) ? Eu[i] : Ei[i - N_USERS * DIM / 4];
    Eb[i] = make_uint2(pack2(x.x, x.y), pack2(x.z, x.w));
}

// ---------- pass 1: bin edges by row block ----------
__global__ void p1_bin(const int* __restrict__ rows,
                       const int* __restrict__ cols,
                       const float* __restrict__ vals,
                       int* __restrict__ bin_cursor,
                       int2* __restrict__ binned,
                       int* __restrict__ g_cnt,
                       int4* __restrict__ G) {
    __shared__ int h[NBINS];
    __shared__ int lcur[NBINS];
    int tid = threadIdx.x;
    for (int i = tid; i < NBINS; i += 256) { h[i] = 0; lcur[i] = 0; }
    __syncthreads();
    int base_e = blockIdx.x * EPB;
    int re[EPT]; int ce[EPT]; float ve[EPT];
#pragma unroll
    for (int k = 0; k < EPT; ++k) {
        int e = base_e + k * 256 + tid;
        if (e < NNZ) {
            re[k] = rows[e]; ce[k] = cols[e]; ve[k] = vals[e];
            atomicAdd(&h[re[k] >> BIN_SHIFT], 1);
        } else {
            re[k] = -1; ce[k] = 0; ve[k] = 0.f;
        }
    }
    __syncthreads();
    for (int i = tid; i < NBINS; i += 256) h[i] = atomicAdd(&bin_cursor[i], h[i]);
    __syncthreads();
#pragma unroll
    for (int k = 0; k < EPT; ++k) {
        if (re[k] >= 0) {
            int b = re[k] >> BIN_SHIFT;
            int off = h[b] + atomicAdd(&lcur[b], 1);
            if (off < CAPB) {
                binned[(size_t)b * CAPB + off] =
                    make_int2((ce[k] << BIN_SHIFT) | (re[k] & (BIN_ROWS - 1)),
                              __float_as_int(ve[k]));
            } else {                                     // statistically impossible; correctness path
                int p = atomicAdd(g_cnt, 1);
                if (p < G_MAX) G[p] = make_int4(re[k], ce[k], __float_as_int(ve[k]), 0);
            }
        }
    }
}

// ---------- pass 2: build 512 bucket rows (+ext) per bin in LDS ----------
// Row format (32 ints / 128 B): [cnt_full, pad, c0, v0, ..., c14, v14]
__global__ __launch_bounds__(1024)
void p2_fill(const int* __restrict__ bin_cursor,
             const int2* __restrict__ binned,
             int* __restrict__ buckets,
             int2* __restrict__ ext) {
    __shared__ int  cnt_s[BIN_ROWS];
    __shared__ int2 rowbuf[BIN_ROWS * CAPR];             // 60 KB
    int bin = blockIdx.x, tid = threadIdx.x;
    for (int i = tid; i < BIN_ROWS; i += 1024) cnt_s[i] = 0;
    __syncthreads();
    int n = bin_cursor[bin]; if (n > CAPB) n = CAPB;
    for (int i = tid; i < n; i += 1024) {
        int2 cv = binned[(size_t)bin * CAPB + i];
        int r = cv.x & (BIN_ROWS - 1);
        int c = (int)(((unsigned)cv.x) >> BIN_SHIFT);
        int slot = atomicAdd(&cnt_s[r], 1);
        if (slot < CAPR) {
            rowbuf[r * CAPR + slot] = make_int2(c, cv.y);
        } else if (slot < CAPR + CAPE) {
            ext[(size_t)(bin * BIN_ROWS + r) * CAPE + (slot - CAPR)] = make_int2(c, cv.y);
        }
        // slot >= CAPR+CAPE: dropped; gather recomputes that row via bin scan
    }
    __syncthreads();
    int4* dst = (int4*)(buckets + (size_t)bin * BIN_ROWS * 32);
    for (int idx = tid; idx < BIN_ROWS * 8; idx += 1024) {
        int r = idx >> 3, q = idx & 7;
        int4 o;
        if (q == 0) {
            int2 t = rowbuf[r * CAPR];
            o = make_int4(cnt_s[r], 0, t.x, t.y);        // full count (may exceed CAPR)
        } else {
            int2 a = rowbuf[r * CAPR + 2 * q - 1];
            int2 b = rowbuf[r * CAPR + 2 * q];
            o = make_int4(a.x, a.y, b.x, b.y);
        }
        dst[idx] = o;
    }
}

// ---------- SpMM gather (bf16): load-all-then-FMA to maximize MLP ----------
__global__ void spmm_gather16(const int* __restrict__ buckets,
                              const int2* __restrict__ ext,
                              const int* __restrict__ bin_cursor,
                              const int2* __restrict__ binned,
                              const int* __restrict__ g_cnt,
                              const int4* __restrict__ G,
                              const ushortT* __restrict__ F,
                              ushortT* __restrict__ out) {
    int gt = blockIdx.x * blockDim.x + threadIdx.x;
    int wid = gt >> 6;
    int lane = threadIdx.x & 63;
    if (wid >= N_NODES) return;
    const int2* row = (const int2*)(buckets + (size_t)wid * 32);
    int2 cv = (lane < 16) ? row[lane] : make_int2(0, 0);
    int cnt = __builtin_amdgcn_readlane(cv.x, 0);        // SGPR, wave-uniform
    float acc = 0.f;
    if (cnt <= CAPR + CAPE) {
        int nb = (cnt < CAPR) ? cnt : CAPR;              // scalar
        // ---- phase 1: issue all 15 loads (independent dests -> all in flight) ----
        ushortT f[CAPR];
        float   v[CAPR];
#pragma unroll
        for (int k = 0; k < CAPR; ++k) {
            int cs = __builtin_amdgcn_readlane(cv.x, k + 1);   // SGPR
            int vi = __builtin_amdgcn_readlane(cv.y, k + 1);   // SGPR
            int   c = (k < nb) ? cs : 0;                 // dummy -> row 0 (L1-hot)
            v[k] = (k < nb) ? __int_as_float(vi) : 0.f;
            f[k] = F[((size_t)c << 6) + lane];
        }
        // ---- phase 2: FMA chain ----
#pragma unroll
        for (int k = 0; k < CAPR; ++k) acc = fmaf(v[k], bf2f(f[k]), acc);

        if (cnt > CAPR) {
            int ne = cnt - CAPR;                          // <= CAPE, scalar
            int2 evr = (lane < CAPE) ? ext[(size_t)wid * CAPE + lane] : make_int2(0, 0);
            ushortT fe[CAPE];
            float   ve[CAPE];
#pragma unroll
            for (int k = 0; k < CAPE; ++k) {
                int cs = __builtin_amdgcn_readlane(evr.x, k);
                int vi = __builtin_amdgcn_readlane(evr.y, k);
                int   c = (k < ne) ? cs : 0;
                ve[k] = (k < ne) ? __int_as_float(vi) : 0.f;
                fe[k] = F[((size_t)c << 6) + lane];
            }
#pragma unroll
            for (int k = 0; k < CAPE; ++k) acc = fmaf(ve[k], bf2f(fe[k]), acc);
        }
    } else {
        // deg > 23 (P~1.6e-7/row): recompute from the bin's edge list, ballot-compacted
        int bin = wid >> BIN_SHIFT, rloc = wid & (BIN_ROWS - 1);
        int n = bin_cursor[bin]; if (n > CAPB) n = CAPB;
        size_t bb = (size_t)bin * CAPB;
        for (int base = 0; base < n; base += 64) {
            int i = base + lane;
            int2 e = (i < n) ? binned[bb + i] : make_int2(0, 0);
            bool m = (i < n) && ((e.x & (BIN_ROWS - 1)) == rloc);
            unsigned long long mask = __ballot(m);
            while (mask) {
                int src = __ffsll(mask) - 1;
                mask &= mask - 1;
                int ex = __shfl(e.x, src);
                int ev2 = __shfl(e.y, src);
                int c = (int)(((unsigned)ex) >> BIN_SHIFT);
                acc += __int_as_float(ev2) * bf2f(F[(size_t)c * DIM + lane]);
            }
        }
    }
    int gc = *g_cnt;                                      // 0 in practice
    if (gc > 0) {
        if (gc > G_MAX) gc = G_MAX;
        for (int i = 0; i < gc; ++i) {
            int4 t = G[i];
            if (t.x == wid)
                acc += __int_as_float(t.z) * bf2f(F[(size_t)t.y * DIM + lane]);
        }
    }
    out[(size_t)wid * DIM + lane] = f2bf(acc);
}

// ---------- prediction (bf16): 2 batch elements per thread for MLP ----------
__global__ void pred_bf16(const int* __restrict__ u_idx,
                          const int* __restrict__ i_idx,
                          const ushortT* __restrict__ F,
                          const float* __restrict__ bu,
                          const float* __restrict__ bi,
                          const float* __restrict__ mu,
                          float* __restrict__ out) {
    int gid = blockIdx.x * blockDim.x + threadIdx.x;
    int t = gid >> 4;
    int s = gid & 15;
    if (t >= BATCH / 2) return;
    int b0 = t, b1 = t + BATCH / 2;
    int u0 = u_idx[b0], i0 = i_idx[b0];
    int u1 = u_idx[b1], i1 = i_idx[b1];
    // 4 independent 8B loads, all in flight
    ushort4 a0 = *((const ushort4*)(F + ((size_t)u0 << 6)) + s);
    ushort4 c0 = *((const ushort4*)(F + ((size_t)(N_USERS + i0) << 6)) + s);
    ushort4 a1 = *((const ushort4*)(F + ((size_t)u1 << 6)) + s);
    ushort4 c1 = *((const ushort4*)(F + ((size_t)(N_USERS + i1) << 6)) + s);
    float p0 = bf2f(a0.x) * bf2f(c0.x) + bf2f(a0.y) * bf2f(c0.y)
             + bf2f(a0.z) * bf2f(c0.z) + bf2f(a0.w) * bf2f(c0.w);
    float p1 = bf2f(a1.x) * bf2f(c1.x) + bf2f(a1.y) * bf2f(c1.y)
             + bf2f(a1.z) * bf2f(c1.z) + bf2f(a1.w) * bf2f(c1.w);
    p0 += __shfl_xor(p0, 1); p1 += __shfl_xor(p1, 1);
    p0 += __shfl_xor(p0, 2); p1 += __shfl_xor(p1, 2);
    p0 += __shfl_xor(p0, 4); p1 += __shfl_xor(p1, 4);
    p0 += __shfl_xor(p0, 8); p1 += __shfl_xor(p1, 8);
    if (s == 0) {
        out[b0] = p0 + bu[u0] + bi[i0] + mu[0];
        out[b1] = p1 + bu[u1] + bi[i1] + mu[0];
    }
}

// ---------- f32 fallback (ws too small): edge-parallel atomics ----------
__global__ void spmm_scatter(const int* __restrict__ rows,
                             const int* __restrict__ cols,
                             const float* __restrict__ vals,
                             const float* __restrict__ Hu,
                             const float* __restrict__ Hi,
                             float* __restrict__ out) {
    int gid = blockIdx.x * blockDim.x + threadIdx.x;
    int e = gid >> 4;
    int s = gid & 15;
    if (e >= NNZ) return;
    int r = rows[e];
    int c = cols[e];
    float v = vals[e];
    const float* src = (c < N_USERS) ? (Hu + (size_t)c * DIM)
                                     : (Hi + (size_t)(c - N_USERS) * DIM);
    float4 x = *reinterpret_cast<const float4*>(src + s * 4);
    float* dst = out + (size_t)r * DIM + s * 4;
    atomicAdd(dst + 0, v * x.x);
    atomicAdd(dst + 1, v * x.y);
    atomicAdd(dst + 2, v * x.z);
    atomicAdd(dst + 3, v * x.w);
}

__global__ void pred_f32(const int* __restrict__ u_idx,
                         const int* __restrict__ i_idx,
                         const float* __restrict__ U,
                         const float* __restrict__ I,
                         const float* __restrict__ bu,
                         const float* __restrict__ bi,
                         const float* __restrict__ mu,
                         float* __restrict__ out) {
    int gid = blockIdx.x * blockDim.x + threadIdx.x;
    int b = gid >> 4;
    int s = gid & 15;
    if (b >= BATCH) return;
    int u = u_idx[b];
    int it = i_idx[b];
    float4 a = *reinterpret_cast<const float4*>(U + (size_t)u * DIM + s * 4);
    float4 c = *reinterpret_cast<const float4*>(I + (size_t)it * DIM + s * 4);
    float p = a.x * c.x + a.y * c.y + a.z * c.z + a.w * c.w;
    p += __shfl_xor(p, 1);
    p += __shfl_xor(p, 2);
    p += __shfl_xor(p, 4);
    p += __shfl_xor(p, 8);
    if (s == 0) out[b] = p + bu[u] + bi[it] + mu[0];
}

extern "C" void kernel_launch(void* const* d_in, const int* in_sizes, int n_in,
                              void* d_out, int out_size, void* d_ws, size_t ws_size,
                              hipStream_t stream) {
    const int*   u_idx  = (const int*)d_in[0];
    const int*   i_idx  = (const int*)d_in[1];
    const int*   A_rows = (const int*)d_in[2];
    const int*   A_cols = (const int*)d_in[3];
    const float* A_vals = (const float*)d_in[4];
    const float* Eu     = (const float*)d_in[5];
    const float* Ei     = (const float*)d_in[6];
    const float* bu     = (const float*)d_in[7];
    const float* bi     = (const float*)d_in[8];
    const float* mu     = (const float*)d_in[9];
    float* out = (float*)d_out;

    // ---- bf16-path workspace layout (bytes) ----
    char* ws = (char*)d_ws;
    ushortT* H1b       = (ushortT*)(ws);                    // 19,200,000 B
    ushortT* EbH2b     = (ushortT*)(ws + 19200000);         // 19,200,000 B (Eb, then H2b)
    int*     buckets   = (int*)    (ws + 38400000);         // 19,202,048 B
    int2*    binned    = (int2*)   (ws + 57602048);         // 19,202,048 B
    int2*    ext       = (int2*)   (ws + 76804096);         //  9,601,024 B
    int*     bin_cursor= (int*)    (ws + 86405120);         //      2,048 B
    int*     g_cnt     = (int*)    (ws + 86407168);         //         64 B
    int4*    G         = (int4*)   (ws + 86407232);         //    262,144 B
    const size_t NEEDED = 86407232 + (size_t)G_MAX * 16;    // 86,669,376 B

    const int pred_blocks   = ((BATCH / 2) * 16 + 255) / 256;
    const int gather_blocks = (N_NODES * 64) / 256;         // 37500
    const int conv_blocks   = ((N_USERS + N_ITEMS) * DIM / 4 + 255) / 256;

    if (ws_size >= NEEDED) {
        zero_misc<<<1, 512, 0, stream>>>(bin_cursor, g_cnt);
        conv_E<<<conv_blocks, 256, 0, stream>>>((const float4*)Eu, (const float4*)Ei,
                                                (uint2*)EbH2b);
        p1_bin<<<P1_BLOCKS, 256, 0, stream>>>(A_rows, A_cols, A_vals,
                                              bin_cursor, binned, g_cnt, G);
        p2_fill<<<NBINS, 1024, 0, stream>>>(bin_cursor, binned, buckets, ext);

        // Layer 1: H1b = A @ Eb
        spmm_gather16<<<gather_blocks, 256, 0, stream>>>(buckets, ext, bin_cursor, binned,
                                                         g_cnt, G, EbH2b, H1b);
        // Layer 2: H2b = A @ H1b  (H2b overwrites Eb, dead after layer 1)
        spmm_gather16<<<gather_blocks, 256, 0, stream>>>(buckets, ext, bin_cursor, binned,
                                                         g_cnt, G, H1b, EbH2b);

        pred_bf16<<<pred_blocks, 256, 0, stream>>>(u_idx, i_idx, EbH2b, bu, bi, mu, out);
    } else {
        // f32 fallback: edge-parallel atomics (needs 76.8 MB)
        float* H1 = (float*)d_ws;
        float* H2 = H1 + (size_t)N_NODES * DIM;
        const int n4 = 2 * N_NODES * DIM / 4;
        zero_ws<<<(n4 + 255) / 256, 256, 0, stream>>>((float4*)d_ws, n4);
        const int spmm_blocks = (NNZ * 16 + 255) / 256;
        spmm_scatter<<<spmm_blocks, 256, 0, stream>>>(A_rows, A_cols, A_vals, Eu, Ei, H1);
        spmm_scatter<<<spmm_blocks, 256, 0, stream>>>(A_rows, A_cols, A_vals,
                                                      H1, H1 + (size_t)N_USERS * DIM, H2);
        const int pf_blocks = (BATCH * 16 + 255) / 256;
        pred_f32<<<pf_blocks, 256, 0, stream>>>(u_idx, i_idx,
                                                H2, H2 + (size_t)N_USERS * DIM,
                                                bu, bi, mu, out);
    }
}